// Round 8
// baseline (755.441 us; speedup 1.0000x reference)
//
#include <hip/hip_runtime.h>
#include <math.h>

#define NN 50000
#define EE 800000
#define DD 32

// deg packing: one double atomic per edge carries both count and sum(w):
//   pack += 65536.0 + w   ->  count = floor(pack/65536), sumw = pack - 65536*count
__device__ __forceinline__ int pack_count(double p){ return (int)(p * (1.0/65536.0)); }
__device__ __forceinline__ float pack_sumw(double p){ return (float)(p - 65536.0 * (double)pack_count(p)); }

// ---------------- setup kernels ----------------

__global__ __launch_bounds__(256) void k_zero(float* p, int count){
  int i = blockIdx.x*256 + threadIdx.x;
  if (i < count) p[i] = 0.f;
}

__global__ __launch_bounds__(256) void k_hist(const int* __restrict__ node_out,
                                              const float* __restrict__ ew,
                                              double* __restrict__ deg_pack){
  int e = blockIdx.x*256 + threadIdx.x;
  if (e < EE){
    int o = node_out[e];
    atomicAdd(&deg_pack[o], 65536.0 + (double)ew[e]);
  }
}

__global__ __launch_bounds__(256) void k_logsum(const double* __restrict__ deg_pack,
                                                float* __restrict__ logsum){
  __shared__ float sd[256];
  int t = threadIdx.x; int n = blockIdx.x*256 + t;
  float v = 0.f;
  if (n < NN) v = logf(pack_sumw(deg_pack[n]) + 1.f);
  sd[t] = v; __syncthreads();
  for (int off = 128; off > 0; off >>= 1){
    if (t < off) sd[t] += sd[t+off];
    __syncthreads();
  }
  if (t == 0) atomicAdd(logsum, sd[0]);
}

__global__ __launch_bounds__(256) void k_scan1(const double* __restrict__ deg_pack,
                                               int* __restrict__ partials){
  __shared__ int sd[256];
  int t = threadIdx.x; int n = blockIdx.x*256 + t;
  sd[t] = (n < NN) ? pack_count(deg_pack[n]) : 0; __syncthreads();
  for (int off = 128; off > 0; off >>= 1){
    if (t < off) sd[t] += sd[t+off];
    __syncthreads();
  }
  if (t == 0) partials[blockIdx.x] = sd[0];
}

__global__ __launch_bounds__(256) void k_scan2(int* __restrict__ partials, int nb,
                                               int* __restrict__ row_start,
                                               int2* __restrict__ csr){
  __shared__ int sd[256];
  int t = threadIdx.x;
  int v = (t < nb) ? partials[t] : 0;
  sd[t] = v; __syncthreads();
  for (int off = 1; off < 256; off <<= 1){
    int x = (t >= off) ? sd[t-off] : 0;
    __syncthreads();
    sd[t] += x;
    __syncthreads();
  }
  if (t < nb) partials[t] = sd[t] - v;   // exclusive
  if (t == 0) row_start[NN] = EE;
  if (t < 32) csr[EE + t] = make_int2(0, 0);   // zero the pad tail (re-poisoned each call)
}

__global__ __launch_bounds__(256) void k_scan3(const double* __restrict__ deg_pack,
                                               const int* __restrict__ partials,
                                               int* __restrict__ row_start,
                                               int* __restrict__ cursor){
  __shared__ int sd[256];
  int t = threadIdx.x; int n = blockIdx.x*256 + t;
  int v = (n < NN) ? pack_count(deg_pack[n]) : 0;
  sd[t] = v; __syncthreads();
  for (int off = 1; off < 256; off <<= 1){
    int x = (t >= off) ? sd[t-off] : 0;
    __syncthreads();
    sd[t] += x;
    __syncthreads();
  }
  if (n < NN){
    int rs = partials[blockIdx.x] + sd[t] - v;  // exclusive
    row_start[n] = rs; cursor[n] = rs;
  }
}

__global__ __launch_bounds__(256) void k_fillcsr(const int* __restrict__ node_in,
                                                 const int* __restrict__ node_out,
                                                 const float* __restrict__ ew,
                                                 int* __restrict__ cursor,
                                                 int2* __restrict__ csr){
  int e = blockIdx.x*256 + threadIdx.x;
  if (e < EE){
    int o = node_out[e];
    int pos = atomicAdd(&cursor[o], 1);
    int2 v; v.x = node_in[e]; v.y = __float_as_int(ew[e]);
    csr[pos] = v;
  }
}

__global__ __launch_bounds__(256) void k_scales(const double* __restrict__ deg_pack,
                                                const float* __restrict__ logsum,
                                                float* __restrict__ scale_arr,
                                                float* __restrict__ inv_arr){
  int n = blockIdx.x*256 + threadIdx.x;
  if (n < NN){
    float mean = *logsum / (float)NN;
    float s = logf(pack_sumw(deg_pack[n]) + 1.f) / mean;
    scale_arr[n] = s;
    inv_arr[n]   = 1.f / fmaxf(s, 0.01f);
  }
}

// rel_input per layer (6x32) and query-part of final MLP (64)
__global__ __launch_bounds__(256) void k_prep(const float* __restrict__ qw,
                                              const float* __restrict__ rel_W,
                                              const float* __restrict__ rel_b,
                                              const float* __restrict__ W1,
                                              const float* __restrict__ b1,
                                              float* __restrict__ rel6,
                                              float* __restrict__ qc){
  int t = threadIdx.x;
  if (t < 192){
    int l = t >> 5, j = t & 31;
    float s = rel_b[t];
    for (int d = 0; d < 32; ++d) s += qw[d] * rel_W[l*1024 + d*32 + j];
    rel6[t] = s;
  } else if (t < 256){
    int j = t - 192;
    float s = b1[j];
    for (int k = 0; k < 32; ++k) s += qw[k] * W1[(32+k)*64 + j];
    qc[j] = s;
  }
}

__global__ __launch_bounds__(256) void k_init_h(const int* __restrict__ hidx,
                                                float* __restrict__ h,
                                                float* __restrict__ hT){
  int i = blockIdx.x*256 + threadIdx.x;
  int hv = *hidx;
  if (i < NN*DD){
    h[i]  = ((i >> 5) == hv) ? 0.f : 100.f;   // row-major: n = i/32
    int n2 = i % NN;                           // transposed: n = i % N
    hT[i] = (n2 == hv) ? 0.f : 100.f;
  }
}

// t[n] = dot(h[n], rel_layer5) for msg_score
__global__ __launch_bounds__(256) void k_dot(const float* __restrict__ h,
                                             const float* __restrict__ rel6,
                                             float* __restrict__ tdot){
  int n0 = blockIdx.x*256 + threadIdx.x;
  int n = (n0 < NN) ? n0 : NN-1;
  const float* relr = rel6 + 5*32;
  float s = 0.f;
  #pragma unroll
  for (int d = 0; d < 32; ++d) s += h[n*32 + d] * relr[d];
  if (n0 < NN) tdot[n0] = s;
}

// ---------------- fused per-layer kernel ----------------
// Block = 64 nodes, 256 threads = 4 waves; wave w owns nodes [base+16w, +16).
// Phase 1 (agg), WAVE-UNIFORM node-major: lane = (slot = lane>>3 edge slot,
//   quad = lane&7 -> dims quad*4..+3). Per 16-edge step: 2 csr dwordx2 +
//   2 h dwordx4 per lane (one wave inst covers 8 edges), fully coalesced;
//   2 latency waits per 16 edges, zero wave divergence (row_start via s_load).
//   Tail lanes masked with w=0 / +-inf neutrals (sums exact). Node finalize:
//   shfl_xor(8,16,32) slot-reduction of S1/S2/M/m (+best/bi in PRED; per-edge
//   score w*tdot[src] identical to prior rounds -> tie semantics preserved).
// Phase 2: j-split linear (wave-uniform W addresses -> s_load), stats in LDS
//   sh[kp*64 + (node ^ (kp&31))] (2-way = free on reads).
template<bool PRED>
__global__ __launch_bounds__(256, 3) void k_layer(const float* __restrict__ h,
                                               const float* __restrict__ hT,
                                               const float* __restrict__ rel6,
                                               const int* __restrict__ row_start,
                                               const int2* __restrict__ csr,
                                               const int* __restrict__ hidx,
                                               const float* __restrict__ tdot,
                                               const float* __restrict__ lin_W,
                                               const float* __restrict__ lin_b,
                                               const float* __restrict__ scale_arr,
                                               const float* __restrict__ inv_arr,
                                               float* __restrict__ h_next,
                                               float* __restrict__ hT_next,
                                               float* __restrict__ pred_out,
                                               int l){
  __shared__ float sh[128*64];
  int tid = threadIdx.x;
  int base = blockIdx.x * 64;
  int hv0 = *hidx;

  // ---- phase 1: aggregation ----
  {
    int wid  = __builtin_amdgcn_readfirstlane(tid >> 6);
    int lane = tid & 63;
    int slot = lane >> 3;    // edge slot 0..7
    int quad = lane & 7;     // dim group: dims quad*4..+3
    const float* relp = rel6 + l*32 + quad*4;
    float r0 = relp[0], r1 = relp[1], r2 = relp[2], r3 = relp[3];
    int nw0 = base + wid*16;
    for (int i = 0; i < 16; ++i){
      int n = nw0 + i;
      if (n >= NN) break;
      int s0 = row_start[n], s1 = row_start[n+1];   // wave-uniform -> s_load
      float S10=0.f,S11=0.f,S12=0.f,S13=0.f;
      float S20=0.f,S21=0.f,S22=0.f,S23=0.f;
      float M0=-INFINITY,M1=-INFINITY,M2=-INFINITY,M3=-INFINITY;
      float m0=INFINITY,m1=INFINITY,m2=INFINITY,m3=INFINITY;
      float best=-INFINITY; int bi=NN;
      for (int e = s0; e < s1; e += 16){
        int eA = e + slot, eB = e + 8 + slot;
        int2 cA = csr[eA];
        int2 cB = csr[eB];
        bool vA = eA < s1, vB = eB < s1;
        const float* hA = h + cA.x*32 + quad*4;
        const float* hB = h + cB.x*32 + quad*4;
        float a0=hA[0], a1=hA[1], a2=hA[2], a3=hA[3];
        float b0=hB[0], b1=hB[1], b2=hB[2], b3=hB[3];
        float tA=0.f, tB=0.f;
        if (PRED){ tA = tdot[cA.x]; tB = tdot[cB.x]; }
        float wA = vA ? __int_as_float(cA.y) : 0.f;
        float wB = vB ? __int_as_float(cB.y) : 0.f;
        // edge A
        {
          float p0=wA*a0, p1=wA*a1, p2=wA*a2, p3=wA*a3;
          S10+=p0; S11+=p1; S12+=p2; S13+=p3;
          S20+=p0*a0; S21+=p1*a1; S22+=p2*a2; S23+=p3*a3;
          M0=fmaxf(M0, vA?p0:-INFINITY); M1=fmaxf(M1, vA?p1:-INFINITY);
          M2=fmaxf(M2, vA?p2:-INFINITY); M3=fmaxf(M3, vA?p3:-INFINITY);
          m0=fminf(m0, vA?p0: INFINITY); m1=fminf(m1, vA?p1: INFINITY);
          m2=fminf(m2, vA?p2: INFINITY); m3=fminf(m3, vA?p3: INFINITY);
          if (PRED){
            float sv = vA ? wA*tA : -INFINITY;
            int cand = vA ? cA.x : NN;
            if (sv > best){ best = sv; bi = cand; }
            else if (sv == best && cand < bi) bi = cand;
          }
        }
        // edge B
        {
          float p0=wB*b0, p1=wB*b1, p2=wB*b2, p3=wB*b3;
          S10+=p0; S11+=p1; S12+=p2; S13+=p3;
          S20+=p0*b0; S21+=p1*b1; S22+=p2*b2; S23+=p3*b3;
          M0=fmaxf(M0, vB?p0:-INFINITY); M1=fmaxf(M1, vB?p1:-INFINITY);
          M2=fmaxf(M2, vB?p2:-INFINITY); M3=fmaxf(M3, vB?p3:-INFINITY);
          m0=fminf(m0, vB?p0: INFINITY); m1=fminf(m1, vB?p1: INFINITY);
          m2=fminf(m2, vB?p2: INFINITY); m3=fminf(m3, vB?p3: INFINITY);
          if (PRED){
            float sv = vB ? wB*tB : -INFINITY;
            int cand = vB ? cB.x : NN;
            if (sv > best){ best = sv; bi = cand; }
            else if (sv == best && cand < bi) bi = cand;
          }
        }
      }
      // cross-slot reduction (lanes differing in bits 3,4,5)
      #pragma unroll
      for (int d = 8; d <= 32; d <<= 1){
        S10 += __shfl_xor(S10, d); S11 += __shfl_xor(S11, d);
        S12 += __shfl_xor(S12, d); S13 += __shfl_xor(S13, d);
        S20 += __shfl_xor(S20, d); S21 += __shfl_xor(S21, d);
        S22 += __shfl_xor(S22, d); S23 += __shfl_xor(S23, d);
        M0 = fmaxf(M0, __shfl_xor(M0, d)); M1 = fmaxf(M1, __shfl_xor(M1, d));
        M2 = fmaxf(M2, __shfl_xor(M2, d)); M3 = fmaxf(M3, __shfl_xor(M3, d));
        m0 = fminf(m0, __shfl_xor(m0, d)); m1 = fminf(m1, __shfl_xor(m1, d));
        m2 = fminf(m2, __shfl_xor(m2, d)); m3 = fminf(m3, __shfl_xor(m3, d));
        if (PRED){
          float ob = __shfl_xor(best, d);
          int  obi = __shfl_xor(bi, d);
          if (ob > best){ best = ob; bi = obi; }
          else if (ob == best && obi < bi) bi = obi;
        }
      }
      // finalize (all lanes hold full-node reductions for their 4 dims)
      float bnd = (n == hv0) ? 0.f : 100.f;
      int deg = s1 - s0;
      float cntf = (float)(deg + 1);
      float mean0,mean1,mean2,mean3, mx0,mx1,mx2,mx3, mn0,mn1,mn2,mn3, sd0,sd1,sd2,sd3;
#define FIN(c, rc, S1c, S2c, Mc, mc) { \
        float em, en; \
        if (deg > 0){ \
          em = (rc >= 0.f) ? rc*Mc : rc*mc; \
          en = (rc >= 0.f) ? rc*mc : rc*Mc; \
          mx##c = fmaxf(em, bnd); mn##c = fminf(en, bnd); \
        } else { mx##c = bnd; mn##c = bnd; } \
        mean##c = (rc*S1c + bnd) / cntf; \
        float sq = (rc*rc*S2c + bnd*bnd) / cntf; \
        sd##c = sqrtf(fmaxf(sq - mean##c*mean##c, 1e-6f)); }
      FIN(0, r0, S10, S20, M0, m0)
      FIN(1, r1, S11, S21, M1, m1)
      FIN(2, r2, S12, S22, M2, m2)
      FIN(3, r3, S13, S23, M3, m3)
#undef FIN
      if (PRED){
        float ss = (n == hv0) ? 0.f : 3200.f;   // boundary self-loop row sum, w=1
        if (ss > best){ best = ss; bi = n; }
        else if (ss == best && n < bi) bi = n;
        if (lane == 0) pred_out[n] = (float)bi;
      }
      if (slot < 4){
        int nl = n - base;
        float v0 = (slot==0)?mean0 : (slot==1)?mx0 : (slot==2)?mn0 : sd0;
        float v1 = (slot==0)?mean1 : (slot==1)?mx1 : (slot==2)?mn1 : sd1;
        float v2 = (slot==0)?mean2 : (slot==1)?mx2 : (slot==2)?mn2 : sd2;
        float v3 = (slot==0)?mean3 : (slot==1)?mx3 : (slot==2)?mn3 : sd3;
        int kp0 = (quad*4+0)*4 + slot;
        int kp1 = (quad*4+1)*4 + slot;
        int kp2 = (quad*4+2)*4 + slot;
        int kp3 = (quad*4+3)*4 + slot;
        sh[kp0*64 + (nl ^ (kp0 & 31))] = v0;
        sh[kp1*64 + (nl ^ (kp1 & 31))] = v1;
        sh[kp2*64 + (nl ^ (kp2 & 31))] = v2;
        sh[kp3*64 + (nl ^ (kp3 & 31))] = v3;
      }
    }
  }
  __syncthreads();

  // ---- phase 2: linear ----
  {
    const float* Wl = lin_W + (size_t)l * 13312;   // 416*32
    int lane = tid & 63;
    int j0 = __builtin_amdgcn_readfirstlane((tid >> 6) * 8);  // 0,8,16,24
    int n0 = base + lane;
    int n = (n0 < NN) ? n0 : NN-1;
    float sc = scale_arr[n], iv = inv_arr[n];
    float acc[8];
    #pragma unroll
    for (int j = 0; j < 8; ++j) acc[j] = lin_b[l*32 + j0 + j];

    for (int k = 0; k < 32; ++k){
      float xv = hT[k*NN + n];
      const float* wr = Wl + k*32 + j0;
      #pragma unroll
      for (int j = 0; j < 8; ++j) acc[j] += xv * wr[j];
    }
    for (int kp = 0; kp < 128; ++kp){
      float f = sh[kp*64 + (lane ^ (kp & 31))];
      int d = kp >> 2, c = kp & 3;
      const float* wr = Wl + (32 + d*12 + c*3)*32 + j0;
      float f1 = f*sc, f2 = f*iv;
      #pragma unroll
      for (int j = 0; j < 8; ++j)
        acc[j] += f*wr[j] + f1*wr[32+j] + f2*wr[64+j];
    }

    if (n0 < NN){
      #pragma unroll
      for (int j = 0; j < 8; ++j){
        float v = fmaxf(acc[j], 0.f);
        h_next[n0*32 + j0 + j] = v;
        hT_next[(j0+j)*NN + n0] = v;
      }
    }
  }
}

// ---------------- final MLP ----------------
__global__ __launch_bounds__(256) void k_mlp(const float* __restrict__ hT,
                                             const float* __restrict__ qc,
                                             const float* __restrict__ W1,
                                             const float* __restrict__ W2,
                                             const float* __restrict__ b2,
                                             float* __restrict__ out_score){
  int n0 = blockIdx.x*256 + threadIdx.x;
  int n = (n0 < NN) ? n0 : NN-1;
  float acc[64];
  #pragma unroll
  for (int j = 0; j < 64; ++j) acc[j] = qc[j];
  for (int k = 0; k < 32; ++k){
    float xv = hT[k*NN + n];
    const float* wr = W1 + k*64;
    #pragma unroll
    for (int j = 0; j < 64; ++j) acc[j] += xv * wr[j];
  }
  float s = b2[0];
  #pragma unroll
  for (int j = 0; j < 64; ++j) s += fmaxf(acc[j], 0.f) * W2[j];
  if (n0 < NN) out_score[n0] = s;
}

// ---------------- host launch ----------------
extern "C" void kernel_launch(void* const* d_in, const int* in_sizes, int n_in,
                              void* d_out, int out_size, void* d_ws, size_t ws_size,
                              hipStream_t stream){
  const int*   node_in  = (const int*)d_in[0];
  const int*   node_out = (const int*)d_in[1];
  const float* ew       = (const float*)d_in[2];
  const int*   hidx     = (const int*)d_in[3];
  const float* qw       = (const float*)d_in[4];
  const float* rel_W    = (const float*)d_in[5];
  const float* rel_b    = (const float*)d_in[6];
  const float* lin_W    = (const float*)d_in[7];
  const float* lin_b    = (const float*)d_in[8];
  const float* W1       = (const float*)d_in[9];
  const float* b1       = (const float*)d_in[10];
  const float* W2       = (const float*)d_in[11];
  const float* b2       = (const float*)d_in[12];
  float* out_score = (float*)d_out;
  float* out_pred  = out_score + NN;

  char* w = (char*)d_ws;
  size_t off = 0;
  auto take = [&](size_t bytes)->char*{
    char* p = w + off;
    off = (off + bytes + 255) & ~(size_t)255;
    return p;
  };
  double* deg_pack = (double*)take((size_t)NN*8 + 64*4);
  float*  logsum   = (float*)(deg_pack + NN);
  int*   row_start = (int*)take((size_t)(NN+1)*4);
  int*   cursor    = (int*)take((size_t)NN*4);
  int*   partials  = (int*)take(256*4);
  float* rel6      = (float*)take(192*4);
  float* qc        = (float*)take(64*4);
  float* scale_arr = (float*)take((size_t)NN*4);
  float* inv_arr   = (float*)take((size_t)NN*4);
  float* tdot      = (float*)take((size_t)NN*4);
  int2*  csr       = (int2*)take((size_t)(EE+32)*8);
  float* h_a       = (float*)take((size_t)NN*32*4);
  float* hT_a      = (float*)take((size_t)NN*32*4);
  float* h_b       = (float*)take((size_t)NN*32*4);
  float* hT_b      = (float*)take((size_t)NN*32*4);

  int zc = 2*NN + 64;   // N doubles == 2N floats, + logsum block
  int nb = (NN + 255) / 256;   // 196
  int nlb = (NN + 63) / 64;    // 782
  k_zero   <<<(zc+255)/256, 256, 0, stream>>>((float*)deg_pack, zc);
  k_hist   <<<(EE+255)/256, 256, 0, stream>>>(node_out, ew, deg_pack);
  k_logsum <<<nb, 256, 0, stream>>>(deg_pack, logsum);
  k_scan1  <<<nb, 256, 0, stream>>>(deg_pack, partials);
  k_scan2  <<<1, 256, 0, stream>>>(partials, nb, row_start, csr);
  k_scan3  <<<nb, 256, 0, stream>>>(deg_pack, partials, row_start, cursor);
  k_fillcsr<<<(EE+255)/256, 256, 0, stream>>>(node_in, node_out, ew, cursor, csr);
  k_scales <<<nb, 256, 0, stream>>>(deg_pack, logsum, scale_arr, inv_arr);
  k_prep   <<<1, 256, 0, stream>>>(qw, rel_W, rel_b, W1, b1, rel6, qc);
  k_init_h <<<(NN*DD+255)/256, 256, 0, stream>>>(hidx, h_a, hT_a);

  float* hc = h_a;  float* hTc = hT_a;
  float* hn = h_b;  float* hTn = hT_b;
  for (int l = 0; l < 6; ++l){
    if (l == 5){
      k_dot<<<nb, 256, 0, stream>>>(hc, rel6, tdot);
      k_layer<true><<<nlb, 256, 0, stream>>>(hc, hTc, rel6, row_start, csr,
                                             hidx, tdot, lin_W, lin_b,
                                             scale_arr, inv_arr, hn, hTn,
                                             out_pred, l);
    } else {
      k_layer<false><<<nlb, 256, 0, stream>>>(hc, hTc, rel6, row_start, csr,
                                              hidx, tdot, lin_W, lin_b,
                                              scale_arr, inv_arr, hn, hTn,
                                              out_pred, l);
    }
    float* t1 = hc;  hc = hn;  hn = t1;
    float* t2 = hTc; hTc = hTn; hTn = t2;
  }
  k_mlp<<<nb, 256, 0, stream>>>(hTc, qc, W1, W2, b2, out_score);
}

// Round 9
// 734.351 us; speedup vs baseline: 1.0287x; 1.0287x over previous
//
#include <hip/hip_runtime.h>
#include <math.h>

#define NN 50000
#define EE 800000
#define DD 32

// deg packing: one double atomic per edge carries both count and sum(w):
//   pack += 65536.0 + w   ->  count = floor(pack/65536), sumw = pack - 65536*count
__device__ __forceinline__ int pack_count(double p){ return (int)(p * (1.0/65536.0)); }
__device__ __forceinline__ float pack_sumw(double p){ return (float)(p - 65536.0 * (double)pack_count(p)); }

// ---------------- setup kernels ----------------

__global__ __launch_bounds__(256) void k_zero(float* p, int count){
  int i = blockIdx.x*256 + threadIdx.x;
  if (i < count) p[i] = 0.f;
}

__global__ __launch_bounds__(256) void k_hist(const int* __restrict__ node_out,
                                              const float* __restrict__ ew,
                                              double* __restrict__ deg_pack){
  int e = blockIdx.x*256 + threadIdx.x;
  if (e < EE){
    int o = node_out[e];
    atomicAdd(&deg_pack[o], 65536.0 + (double)ew[e]);
  }
}

__global__ __launch_bounds__(256) void k_logsum(const double* __restrict__ deg_pack,
                                                float* __restrict__ logsum){
  __shared__ float sd[256];
  int t = threadIdx.x; int n = blockIdx.x*256 + t;
  float v = 0.f;
  if (n < NN) v = logf(pack_sumw(deg_pack[n]) + 1.f);
  sd[t] = v; __syncthreads();
  for (int off = 128; off > 0; off >>= 1){
    if (t < off) sd[t] += sd[t+off];
    __syncthreads();
  }
  if (t == 0) atomicAdd(logsum, sd[0]);
}

__global__ __launch_bounds__(256) void k_scan1(const double* __restrict__ deg_pack,
                                               int* __restrict__ partials){
  __shared__ int sd[256];
  int t = threadIdx.x; int n = blockIdx.x*256 + t;
  sd[t] = (n < NN) ? pack_count(deg_pack[n]) : 0; __syncthreads();
  for (int off = 128; off > 0; off >>= 1){
    if (t < off) sd[t] += sd[t+off];
    __syncthreads();
  }
  if (t == 0) partials[blockIdx.x] = sd[0];
}

__global__ __launch_bounds__(256) void k_scan2(int* __restrict__ partials, int nb,
                                               int* __restrict__ row_start,
                                               int2* __restrict__ csr){
  __shared__ int sd[256];
  int t = threadIdx.x;
  int v = (t < nb) ? partials[t] : 0;
  sd[t] = v; __syncthreads();
  for (int off = 1; off < 256; off <<= 1){
    int x = (t >= off) ? sd[t-off] : 0;
    __syncthreads();
    sd[t] += x;
    __syncthreads();
  }
  if (t < nb) partials[t] = sd[t] - v;   // exclusive
  if (t == 0) row_start[NN] = EE;
  if (t < 32) csr[EE + t] = make_int2(0, 0);   // zero the pad tail (re-poisoned each call)
}

__global__ __launch_bounds__(256) void k_scan3(const double* __restrict__ deg_pack,
                                               const int* __restrict__ partials,
                                               int* __restrict__ row_start,
                                               int* __restrict__ cursor){
  __shared__ int sd[256];
  int t = threadIdx.x; int n = blockIdx.x*256 + t;
  int v = (n < NN) ? pack_count(deg_pack[n]) : 0;
  sd[t] = v; __syncthreads();
  for (int off = 1; off < 256; off <<= 1){
    int x = (t >= off) ? sd[t-off] : 0;
    __syncthreads();
    sd[t] += x;
    __syncthreads();
  }
  if (n < NN){
    int rs = partials[blockIdx.x] + sd[t] - v;  // exclusive
    row_start[n] = rs; cursor[n] = rs;
  }
}

__global__ __launch_bounds__(256) void k_fillcsr(const int* __restrict__ node_in,
                                                 const int* __restrict__ node_out,
                                                 const float* __restrict__ ew,
                                                 int* __restrict__ cursor,
                                                 int2* __restrict__ csr){
  int e = blockIdx.x*256 + threadIdx.x;
  if (e < EE){
    int o = node_out[e];
    int pos = atomicAdd(&cursor[o], 1);
    int2 v; v.x = node_in[e]; v.y = __float_as_int(ew[e]);
    csr[pos] = v;
  }
}

__global__ __launch_bounds__(256) void k_scales(const double* __restrict__ deg_pack,
                                                const float* __restrict__ logsum,
                                                float* __restrict__ scale_arr,
                                                float* __restrict__ inv_arr){
  int n = blockIdx.x*256 + threadIdx.x;
  if (n < NN){
    float mean = *logsum / (float)NN;
    float s = logf(pack_sumw(deg_pack[n]) + 1.f) / mean;
    scale_arr[n] = s;
    inv_arr[n]   = 1.f / fmaxf(s, 0.01f);
  }
}

// rel_input per layer (6x32) and query-part of final MLP (64)
__global__ __launch_bounds__(256) void k_prep(const float* __restrict__ qw,
                                              const float* __restrict__ rel_W,
                                              const float* __restrict__ rel_b,
                                              const float* __restrict__ W1,
                                              const float* __restrict__ b1,
                                              float* __restrict__ rel6,
                                              float* __restrict__ qc){
  int t = threadIdx.x;
  if (t < 192){
    int l = t >> 5, j = t & 31;
    float s = rel_b[t];
    for (int d = 0; d < 32; ++d) s += qw[d] * rel_W[l*1024 + d*32 + j];
    rel6[t] = s;
  } else if (t < 256){
    int j = t - 192;
    float s = b1[j];
    for (int k = 0; k < 32; ++k) s += qw[k] * W1[(32+k)*64 + j];
    qc[j] = s;
  }
}

__global__ __launch_bounds__(256) void k_init_h(const int* __restrict__ hidx,
                                                float* __restrict__ h,
                                                float* __restrict__ hT){
  int i = blockIdx.x*256 + threadIdx.x;
  int hv = *hidx;
  if (i < NN*DD){
    h[i]  = ((i >> 5) == hv) ? 0.f : 100.f;   // row-major: n = i/32
    int n2 = i % NN;                           // transposed: n = i % N
    hT[i] = (n2 == hv) ? 0.f : 100.f;
  }
}

// t[n] = dot(h[n], rel_layer5) for msg_score
__global__ __launch_bounds__(256) void k_dot(const float* __restrict__ h,
                                             const float* __restrict__ rel6,
                                             float* __restrict__ tdot){
  int n0 = blockIdx.x*256 + threadIdx.x;
  int n = (n0 < NN) ? n0 : NN-1;
  const float* relr = rel6 + 5*32;
  float s = 0.f;
  #pragma unroll
  for (int d = 0; d < 32; ++d) s += h[n*32 + d] * relr[d];
  if (n0 < NN) tdot[n0] = s;
}

// ---------------- fused per-layer kernel ----------------
// Block = 32 nodes, 256 threads = 4 waves; wave w owns nodes [base+8w, +8).
// Grid 1563 blocks (~6.1/CU -> ~24 waves/CU; launch_bounds(256,6) keeps the
// register allocator from capping below that). LDS stride 33 (16.9 KB):
// conflict-free phase-2 reads, 4-way on the tiny per-node stores.
// Phase 1 (agg), wave-uniform node-major: lane = (slot=lane>>3 edge slot,
//   quad=lane&7 -> dims quad*4..+3). Per 16-edge step: 2 csr dwordx2
//   (pipelined ONE STEP AHEAD - only 2 int2 rotate) + 2 h dwordx4; only the
//   h-gather latency is exposed per step. Zero wave divergence (row_start
//   via s_load). Tail lanes masked with w=0 / +-inf neutrals. Node finalize:
//   shfl_xor(8,16,32) slot-reduction (PRED: per-edge score w*tdot[src]
//   bit-identical to prior rounds -> tie semantics preserved).
// Phase 2: j-split linear (wave-uniform W addresses -> s_load), lanes 0-31
//   active (node = base+lane).
template<bool PRED>
__global__ __launch_bounds__(256, 6) void k_layer(const float* __restrict__ h,
                                               const float* __restrict__ hT,
                                               const float* __restrict__ rel6,
                                               const int* __restrict__ row_start,
                                               const int2* __restrict__ csr,
                                               const int* __restrict__ hidx,
                                               const float* __restrict__ tdot,
                                               const float* __restrict__ lin_W,
                                               const float* __restrict__ lin_b,
                                               const float* __restrict__ scale_arr,
                                               const float* __restrict__ inv_arr,
                                               float* __restrict__ h_next,
                                               float* __restrict__ hT_next,
                                               float* __restrict__ pred_out,
                                               int l){
  __shared__ float sh[128*33];
  int tid = threadIdx.x;
  int base = blockIdx.x * 32;
  int hv0 = *hidx;

  // ---- phase 1: aggregation ----
  {
    int wid  = __builtin_amdgcn_readfirstlane(tid >> 6);
    int lane = tid & 63;
    int slot = lane >> 3;    // edge slot 0..7
    int quad = lane & 7;     // dim group: dims quad*4..+3
    const float* relp = rel6 + l*32 + quad*4;
    float r0 = relp[0], r1 = relp[1], r2 = relp[2], r3 = relp[3];
    int nw0 = base + wid*8;
    for (int i = 0; i < 8; ++i){
      int n = nw0 + i;
      if (n >= NN) break;
      int s0 = row_start[n], s1 = row_start[n+1];   // wave-uniform -> s_load
      float S10=0.f,S11=0.f,S12=0.f,S13=0.f;
      float S20=0.f,S21=0.f,S22=0.f,S23=0.f;
      float M0=-INFINITY,M1=-INFINITY,M2=-INFINITY,M3=-INFINITY;
      float m0=INFINITY,m1=INFINITY,m2=INFINITY,m3=INFINITY;
      float best=-INFINITY; int bi=NN;
      // csr pipelined one step ahead (pad covers reads past s1)
      int2 cA = csr[s0 + slot];
      int2 cB = csr[s0 + 8 + slot];
      for (int e = s0; e < s1; e += 16){
        // h gathers for current csr (csr already in regs from previous step)
        const float4* hA = (const float4*)(h + cA.x*32);
        const float4* hB = (const float4*)(h + cB.x*32);
        float4 a = hA[quad];
        float4 b = hB[quad];
        float tA=0.f, tB=0.f;
        if (PRED){ tA = tdot[cA.x]; tB = tdot[cB.x]; }
        // prefetch next step's csr (rotates only 2 int2)
        int2 nA = csr[e + 16 + slot];
        int2 nB = csr[e + 24 + slot];
        bool vA = e + slot < s1, vB = e + 8 + slot < s1;
        float wA = vA ? __int_as_float(cA.y) : 0.f;
        float wB = vB ? __int_as_float(cB.y) : 0.f;
        // edge A
        {
          float p0=wA*a.x, p1=wA*a.y, p2=wA*a.z, p3=wA*a.w;
          S10+=p0; S11+=p1; S12+=p2; S13+=p3;
          S20+=p0*a.x; S21+=p1*a.y; S22+=p2*a.z; S23+=p3*a.w;
          M0=fmaxf(M0, vA?p0:-INFINITY); M1=fmaxf(M1, vA?p1:-INFINITY);
          M2=fmaxf(M2, vA?p2:-INFINITY); M3=fmaxf(M3, vA?p3:-INFINITY);
          m0=fminf(m0, vA?p0: INFINITY); m1=fminf(m1, vA?p1: INFINITY);
          m2=fminf(m2, vA?p2: INFINITY); m3=fminf(m3, vA?p3: INFINITY);
          if (PRED){
            float sv = vA ? wA*tA : -INFINITY;
            int cand = vA ? cA.x : NN;
            if (sv > best){ best = sv; bi = cand; }
            else if (sv == best && cand < bi) bi = cand;
          }
        }
        // edge B
        {
          float p0=wB*b.x, p1=wB*b.y, p2=wB*b.z, p3=wB*b.w;
          S10+=p0; S11+=p1; S12+=p2; S13+=p3;
          S20+=p0*b.x; S21+=p1*b.y; S22+=p2*b.z; S23+=p3*b.w;
          M0=fmaxf(M0, vB?p0:-INFINITY); M1=fmaxf(M1, vB?p1:-INFINITY);
          M2=fmaxf(M2, vB?p2:-INFINITY); M3=fmaxf(M3, vB?p3:-INFINITY);
          m0=fminf(m0, vB?p0: INFINITY); m1=fminf(m1, vB?p1: INFINITY);
          m2=fminf(m2, vB?p2: INFINITY); m3=fminf(m3, vB?p3: INFINITY);
          if (PRED){
            float sv = vB ? wB*tB : -INFINITY;
            int cand = vB ? cB.x : NN;
            if (sv > best){ best = sv; bi = cand; }
            else if (sv == best && cand < bi) bi = cand;
          }
        }
        cA = nA; cB = nB;
      }
      // cross-slot reduction (lanes differing in bits 3,4,5)
      #pragma unroll
      for (int d = 8; d <= 32; d <<= 1){
        S10 += __shfl_xor(S10, d); S11 += __shfl_xor(S11, d);
        S12 += __shfl_xor(S12, d); S13 += __shfl_xor(S13, d);
        S20 += __shfl_xor(S20, d); S21 += __shfl_xor(S21, d);
        S22 += __shfl_xor(S22, d); S23 += __shfl_xor(S23, d);
        M0 = fmaxf(M0, __shfl_xor(M0, d)); M1 = fmaxf(M1, __shfl_xor(M1, d));
        M2 = fmaxf(M2, __shfl_xor(M2, d)); M3 = fmaxf(M3, __shfl_xor(M3, d));
        m0 = fminf(m0, __shfl_xor(m0, d)); m1 = fminf(m1, __shfl_xor(m1, d));
        m2 = fminf(m2, __shfl_xor(m2, d)); m3 = fminf(m3, __shfl_xor(m3, d));
        if (PRED){
          float ob = __shfl_xor(best, d);
          int  obi = __shfl_xor(bi, d);
          if (ob > best){ best = ob; bi = obi; }
          else if (ob == best && obi < bi) bi = obi;
        }
      }
      // finalize (all lanes hold full-node reductions for their 4 dims)
      float bnd = (n == hv0) ? 0.f : 100.f;
      int deg = s1 - s0;
      float cntf = (float)(deg + 1);
      float mean0,mean1,mean2,mean3, mx0,mx1,mx2,mx3, mn0,mn1,mn2,mn3, sd0,sd1,sd2,sd3;
#define FIN(c, rc, S1c, S2c, Mc, mc) { \
        float em, en; \
        if (deg > 0){ \
          em = (rc >= 0.f) ? rc*Mc : rc*mc; \
          en = (rc >= 0.f) ? rc*mc : rc*Mc; \
          mx##c = fmaxf(em, bnd); mn##c = fminf(en, bnd); \
        } else { mx##c = bnd; mn##c = bnd; } \
        mean##c = (rc*S1c + bnd) / cntf; \
        float sq = (rc*rc*S2c + bnd*bnd) / cntf; \
        sd##c = sqrtf(fmaxf(sq - mean##c*mean##c, 1e-6f)); }
      FIN(0, r0, S10, S20, M0, m0)
      FIN(1, r1, S11, S21, M1, m1)
      FIN(2, r2, S12, S22, M2, m2)
      FIN(3, r3, S13, S23, M3, m3)
#undef FIN
      if (PRED){
        float ss = (n == hv0) ? 0.f : 3200.f;   // boundary self-loop row sum, w=1
        if (ss > best){ best = ss; bi = n; }
        else if (ss == best && n < bi) bi = n;
        if (lane == 0) pred_out[n] = (float)bi;
      }
      if (slot < 4){
        int nl = n - base;
        float v0 = (slot==0)?mean0 : (slot==1)?mx0 : (slot==2)?mn0 : sd0;
        float v1 = (slot==0)?mean1 : (slot==1)?mx1 : (slot==2)?mn1 : sd1;
        float v2 = (slot==0)?mean2 : (slot==1)?mx2 : (slot==2)?mn2 : sd2;
        float v3 = (slot==0)?mean3 : (slot==1)?mx3 : (slot==2)?mn3 : sd3;
        int kp0 = (quad*4+0)*4 + slot;
        int kp1 = (quad*4+1)*4 + slot;
        int kp2 = (quad*4+2)*4 + slot;
        int kp3 = (quad*4+3)*4 + slot;
        sh[kp0*33 + nl] = v0;
        sh[kp1*33 + nl] = v1;
        sh[kp2*33 + nl] = v2;
        sh[kp3*33 + nl] = v3;
      }
    }
  }
  __syncthreads();

  // ---- phase 2: linear ----
  {
    const float* Wl = lin_W + (size_t)l * 13312;   // 416*32
    int lane = tid & 63;
    int j0 = __builtin_amdgcn_readfirstlane((tid >> 6) * 8);  // 0,8,16,24
    if (lane < 32){
      int n0 = base + lane;
      int n = (n0 < NN) ? n0 : NN-1;
      float sc = scale_arr[n], iv = inv_arr[n];
      float acc[8];
      #pragma unroll
      for (int j = 0; j < 8; ++j) acc[j] = lin_b[l*32 + j0 + j];

      for (int k = 0; k < 32; ++k){
        float xv = hT[k*NN + n];
        const float* wr = Wl + k*32 + j0;
        #pragma unroll
        for (int j = 0; j < 8; ++j) acc[j] += xv * wr[j];
      }
      for (int kp = 0; kp < 128; ++kp){
        float f = sh[kp*33 + lane];
        int d = kp >> 2, c = kp & 3;
        const float* wr = Wl + (32 + d*12 + c*3)*32 + j0;
        float f1 = f*sc, f2 = f*iv;
        #pragma unroll
        for (int j = 0; j < 8; ++j)
          acc[j] += f*wr[j] + f1*wr[32+j] + f2*wr[64+j];
      }

      if (n0 < NN){
        #pragma unroll
        for (int j = 0; j < 8; ++j){
          float v = fmaxf(acc[j], 0.f);
          h_next[n0*32 + j0 + j] = v;
          hT_next[(j0+j)*NN + n0] = v;
        }
      }
    }
  }
}

// ---------------- final MLP ----------------
__global__ __launch_bounds__(256) void k_mlp(const float* __restrict__ hT,
                                             const float* __restrict__ qc,
                                             const float* __restrict__ W1,
                                             const float* __restrict__ W2,
                                             const float* __restrict__ b2,
                                             float* __restrict__ out_score){
  int n0 = blockIdx.x*256 + threadIdx.x;
  int n = (n0 < NN) ? n0 : NN-1;
  float acc[64];
  #pragma unroll
  for (int j = 0; j < 64; ++j) acc[j] = qc[j];
  for (int k = 0; k < 32; ++k){
    float xv = hT[k*NN + n];
    const float* wr = W1 + k*64;
    #pragma unroll
    for (int j = 0; j < 64; ++j) acc[j] += xv * wr[j];
  }
  float s = b2[0];
  #pragma unroll
  for (int j = 0; j < 64; ++j) s += fmaxf(acc[j], 0.f) * W2[j];
  if (n0 < NN) out_score[n0] = s;
}

// ---------------- host launch ----------------
extern "C" void kernel_launch(void* const* d_in, const int* in_sizes, int n_in,
                              void* d_out, int out_size, void* d_ws, size_t ws_size,
                              hipStream_t stream){
  const int*   node_in  = (const int*)d_in[0];
  const int*   node_out = (const int*)d_in[1];
  const float* ew       = (const float*)d_in[2];
  const int*   hidx     = (const int*)d_in[3];
  const float* qw       = (const float*)d_in[4];
  const float* rel_W    = (const float*)d_in[5];
  const float* rel_b    = (const float*)d_in[6];
  const float* lin_W    = (const float*)d_in[7];
  const float* lin_b    = (const float*)d_in[8];
  const float* W1       = (const float*)d_in[9];
  const float* b1       = (const float*)d_in[10];
  const float* W2       = (const float*)d_in[11];
  const float* b2       = (const float*)d_in[12];
  float* out_score = (float*)d_out;
  float* out_pred  = out_score + NN;

  char* w = (char*)d_ws;
  size_t off = 0;
  auto take = [&](size_t bytes)->char*{
    char* p = w + off;
    off = (off + bytes + 255) & ~(size_t)255;
    return p;
  };
  double* deg_pack = (double*)take((size_t)NN*8 + 64*4);
  float*  logsum   = (float*)(deg_pack + NN);
  int*   row_start = (int*)take((size_t)(NN+1)*4);
  int*   cursor    = (int*)take((size_t)NN*4);
  int*   partials  = (int*)take(256*4);
  float* rel6      = (float*)take(192*4);
  float* qc        = (float*)take(64*4);
  float* scale_arr = (float*)take((size_t)NN*4);
  float* inv_arr   = (float*)take((size_t)NN*4);
  float* tdot      = (float*)take((size_t)NN*4);
  int2*  csr       = (int2*)take((size_t)(EE+32)*8);
  float* h_a       = (float*)take((size_t)NN*32*4);
  float* hT_a      = (float*)take((size_t)NN*32*4);
  float* h_b       = (float*)take((size_t)NN*32*4);
  float* hT_b      = (float*)take((size_t)NN*32*4);

  int zc = 2*NN + 64;   // N doubles == 2N floats, + logsum block
  int nb = (NN + 255) / 256;   // 196
  int nlb = (NN + 31) / 32;    // 1563
  k_zero   <<<(zc+255)/256, 256, 0, stream>>>((float*)deg_pack, zc);
  k_hist   <<<(EE+255)/256, 256, 0, stream>>>(node_out, ew, deg_pack);
  k_logsum <<<nb, 256, 0, stream>>>(deg_pack, logsum);
  k_scan1  <<<nb, 256, 0, stream>>>(deg_pack, partials);
  k_scan2  <<<1, 256, 0, stream>>>(partials, nb, row_start, csr);
  k_scan3  <<<nb, 256, 0, stream>>>(deg_pack, partials, row_start, cursor);
  k_fillcsr<<<(EE+255)/256, 256, 0, stream>>>(node_in, node_out, ew, cursor, csr);
  k_scales <<<nb, 256, 0, stream>>>(deg_pack, logsum, scale_arr, inv_arr);
  k_prep   <<<1, 256, 0, stream>>>(qw, rel_W, rel_b, W1, b1, rel6, qc);
  k_init_h <<<(NN*DD+255)/256, 256, 0, stream>>>(hidx, h_a, hT_a);

  float* hc = h_a;  float* hTc = hT_a;
  float* hn = h_b;  float* hTn = hT_b;
  for (int l = 0; l < 6; ++l){
    if (l == 5){
      k_dot<<<nb, 256, 0, stream>>>(hc, rel6, tdot);
      k_layer<true><<<nlb, 256, 0, stream>>>(hc, hTc, rel6, row_start, csr,
                                             hidx, tdot, lin_W, lin_b,
                                             scale_arr, inv_arr, hn, hTn,
                                             out_pred, l);
    } else {
      k_layer<false><<<nlb, 256, 0, stream>>>(hc, hTc, rel6, row_start, csr,
                                              hidx, tdot, lin_W, lin_b,
                                              scale_arr, inv_arr, hn, hTn,
                                              out_pred, l);
    }
    float* t1 = hc;  hc = hn;  hn = t1;
    float* t2 = hTc; hTc = hTn; hTn = t2;
  }
  k_mlp<<<nb, 256, 0, stream>>>(hTc, qc, W1, W2, b2, out_score);
}

// Round 10
// 628.445 us; speedup vs baseline: 1.2021x; 1.1685x over previous
//
#include <hip/hip_runtime.h>
#include <math.h>

#define NN 50000
#define EE 800000
#define DD 32

// deg packing: one double atomic per edge carries both count and sum(w):
//   pack += 65536.0 + w   ->  count = floor(pack/65536), sumw = pack - 65536*count
__device__ __forceinline__ int pack_count(double p){ return (int)(p * (1.0/65536.0)); }
__device__ __forceinline__ float pack_sumw(double p){ return (float)(p - 65536.0 * (double)pack_count(p)); }

// ---------------- setup kernels ----------------

__global__ __launch_bounds__(256) void k_zero(float* p, int count){
  int i = blockIdx.x*256 + threadIdx.x;
  if (i < count) p[i] = 0.f;
}

__global__ __launch_bounds__(256) void k_hist(const int* __restrict__ node_out,
                                              const float* __restrict__ ew,
                                              double* __restrict__ deg_pack){
  int e = blockIdx.x*256 + threadIdx.x;
  if (e < EE){
    int o = node_out[e];
    atomicAdd(&deg_pack[o], 65536.0 + (double)ew[e]);
  }
}

__global__ __launch_bounds__(256) void k_logsum(const double* __restrict__ deg_pack,
                                                float* __restrict__ logsum){
  __shared__ float sd[256];
  int t = threadIdx.x; int n = blockIdx.x*256 + t;
  float v = 0.f;
  if (n < NN) v = logf(pack_sumw(deg_pack[n]) + 1.f);
  sd[t] = v; __syncthreads();
  for (int off = 128; off > 0; off >>= 1){
    if (t < off) sd[t] += sd[t+off];
    __syncthreads();
  }
  if (t == 0) atomicAdd(logsum, sd[0]);
}

__global__ __launch_bounds__(256) void k_scan1(const double* __restrict__ deg_pack,
                                               int* __restrict__ partials){
  __shared__ int sd[256];
  int t = threadIdx.x; int n = blockIdx.x*256 + t;
  sd[t] = (n < NN) ? pack_count(deg_pack[n]) : 0; __syncthreads();
  for (int off = 128; off > 0; off >>= 1){
    if (t < off) sd[t] += sd[t+off];
    __syncthreads();
  }
  if (t == 0) partials[blockIdx.x] = sd[0];
}

__global__ __launch_bounds__(256) void k_scan2(int* __restrict__ partials, int nb,
                                               int* __restrict__ row_start,
                                               int2* __restrict__ csr){
  __shared__ int sd[256];
  int t = threadIdx.x;
  int v = (t < nb) ? partials[t] : 0;
  sd[t] = v; __syncthreads();
  for (int off = 1; off < 256; off <<= 1){
    int x = (t >= off) ? sd[t-off] : 0;
    __syncthreads();
    sd[t] += x;
    __syncthreads();
  }
  if (t < nb) partials[t] = sd[t] - v;   // exclusive
  if (t == 0) row_start[NN] = EE;
  if (t < 32) csr[EE + t] = make_int2(0, 0);   // zero the pad tail (re-poisoned each call)
}

__global__ __launch_bounds__(256) void k_scan3(const double* __restrict__ deg_pack,
                                               const int* __restrict__ partials,
                                               int* __restrict__ row_start,
                                               int* __restrict__ cursor){
  __shared__ int sd[256];
  int t = threadIdx.x; int n = blockIdx.x*256 + t;
  int v = (n < NN) ? pack_count(deg_pack[n]) : 0;
  sd[t] = v; __syncthreads();
  for (int off = 1; off < 256; off <<= 1){
    int x = (t >= off) ? sd[t-off] : 0;
    __syncthreads();
    sd[t] += x;
    __syncthreads();
  }
  if (n < NN){
    int rs = partials[blockIdx.x] + sd[t] - v;  // exclusive
    row_start[n] = rs; cursor[n] = rs;
  }
}

__global__ __launch_bounds__(256) void k_fillcsr(const int* __restrict__ node_in,
                                                 const int* __restrict__ node_out,
                                                 const float* __restrict__ ew,
                                                 int* __restrict__ cursor,
                                                 int2* __restrict__ csr){
  int e = blockIdx.x*256 + threadIdx.x;
  if (e < EE){
    int o = node_out[e];
    int pos = atomicAdd(&cursor[o], 1);
    int2 v; v.x = node_in[e]; v.y = __float_as_int(ew[e]);
    csr[pos] = v;
  }
}

__global__ __launch_bounds__(256) void k_scales(const double* __restrict__ deg_pack,
                                                const float* __restrict__ logsum,
                                                float* __restrict__ scale_arr,
                                                float* __restrict__ inv_arr){
  int n = blockIdx.x*256 + threadIdx.x;
  if (n < NN){
    float mean = *logsum / (float)NN;
    float s = logf(pack_sumw(deg_pack[n]) + 1.f) / mean;
    scale_arr[n] = s;
    inv_arr[n]   = 1.f / fmaxf(s, 0.01f);
  }
}

// rel_input per layer (6x32) and query-part of final MLP (64)
__global__ __launch_bounds__(256) void k_prep(const float* __restrict__ qw,
                                              const float* __restrict__ rel_W,
                                              const float* __restrict__ rel_b,
                                              const float* __restrict__ W1,
                                              const float* __restrict__ b1,
                                              float* __restrict__ rel6,
                                              float* __restrict__ qc){
  int t = threadIdx.x;
  if (t < 192){
    int l = t >> 5, j = t & 31;
    float s = rel_b[t];
    for (int d = 0; d < 32; ++d) s += qw[d] * rel_W[l*1024 + d*32 + j];
    rel6[t] = s;
  } else if (t < 256){
    int j = t - 192;
    float s = b1[j];
    for (int k = 0; k < 32; ++k) s += qw[k] * W1[(32+k)*64 + j];
    qc[j] = s;
  }
}

__global__ __launch_bounds__(256) void k_init_h(const int* __restrict__ hidx,
                                                float* __restrict__ h,
                                                float* __restrict__ hT){
  int i = blockIdx.x*256 + threadIdx.x;
  int hv = *hidx;
  if (i < NN*DD){
    h[i]  = ((i >> 5) == hv) ? 0.f : 100.f;   // row-major: n = i/32
    int n2 = i % NN;                           // transposed: n = i % N
    hT[i] = (n2 == hv) ? 0.f : 100.f;
  }
}

// t[n] = dot(h[n], rel_layer5) for msg_score
__global__ __launch_bounds__(256) void k_dot(const float* __restrict__ h,
                                             const float* __restrict__ rel6,
                                             float* __restrict__ tdot){
  int n0 = blockIdx.x*256 + threadIdx.x;
  int n = (n0 < NN) ? n0 : NN-1;
  const float* relr = rel6 + 5*32;
  float s = 0.f;
  #pragma unroll
  for (int d = 0; d < 32; ++d) s += h[n*32 + d] * relr[d];
  if (n0 < NN) tdot[n0] = s;
}

// ---------------- fused per-layer kernel ----------------
// Block = 32 nodes, 256 threads = 32 groups of 8 lanes; ONE GROUP PER NODE
// (lane quad=tid&7 covers dims quad*4..+3 via float4 -> 8 lanes x 4 dims = 32).
// R9 post-mortem: wave-per-node paid ~250 wave-insts/node in butterfly
// reduction (54 shuffles) -- this structure needs ZERO shuffles: each group's
// accumulators are fully node-reduced by construction. Per edge step: one
// broadcast csr dwordx2 (prefetched 1 ahead) + one h dwordx4 per lane.
// Degree divergence across the 8 groups of a wave costs ~1.6x on edge work
// (edge-work floor is only ~7 us/layer -- cheap vs 40 us of shuffles saved).
// PRED: all 8 lanes compute identical best/bi (broadcast loads) -> no
// reduction; per-edge score w*tdot[src] bit-identical to prior rounds.
// LDS sh[128*33] (16.9 KB): conflict-free phase-2 reads.
// Grid 1563 (~6.1 blocks/CU); launch_bounds(256,6).
template<bool PRED>
__global__ __launch_bounds__(256, 6) void k_layer(const float* __restrict__ h,
                                               const float* __restrict__ hT,
                                               const float* __restrict__ rel6,
                                               const int* __restrict__ row_start,
                                               const int2* __restrict__ csr,
                                               const int* __restrict__ hidx,
                                               const float* __restrict__ tdot,
                                               const float* __restrict__ lin_W,
                                               const float* __restrict__ lin_b,
                                               const float* __restrict__ scale_arr,
                                               const float* __restrict__ inv_arr,
                                               float* __restrict__ h_next,
                                               float* __restrict__ hT_next,
                                               float* __restrict__ pred_out,
                                               int l){
  __shared__ float sh[128*33];
  int tid = threadIdx.x;
  int base = blockIdx.x * 32;
  int hv0 = *hidx;

  // ---- phase 1: aggregation (one 8-lane group per node) ----
  {
    int nl   = tid >> 3;     // group = node index in block, 0..31
    int quad = tid & 7;      // dims quad*4..+3
    int n0 = base + nl;
    bool valid = n0 < NN;
    int n = valid ? n0 : NN-1;
    int s0 = row_start[n], s1 = row_start[n+1];
    float4 r4 = ((const float4*)(rel6 + l*32))[quad];
    float S10=0.f,S11=0.f,S12=0.f,S13=0.f;
    float S20=0.f,S21=0.f,S22=0.f,S23=0.f;
    float M0=-INFINITY,M1=-INFINITY,M2=-INFINITY,M3=-INFINITY;
    float m0=INFINITY,m1=INFINITY,m2=INFINITY,m3=INFINITY;
    float best=-INFINITY; int bi=NN;
    int2 c = csr[s0];                      // pad covers s0==EE
    for (int e = s0; e < s1; ++e){
      const float4* hp = (const float4*)(h + c.x*32);
      float4 a = hp[quad];
      float t = 0.f;
      if (PRED) t = tdot[c.x];
      int2 nx = csr[e+1];                  // pad covers e+1==EE
      float w = __int_as_float(c.y);
      float p0=w*a.x, p1=w*a.y, p2=w*a.z, p3=w*a.w;
      S10+=p0; S11+=p1; S12+=p2; S13+=p3;
      S20+=p0*a.x; S21+=p1*a.y; S22+=p2*a.z; S23+=p3*a.w;
      M0=fmaxf(M0,p0); M1=fmaxf(M1,p1); M2=fmaxf(M2,p2); M3=fmaxf(M3,p3);
      m0=fminf(m0,p0); m1=fminf(m1,p1); m2=fminf(m2,p2); m3=fminf(m3,p3);
      if (PRED){
        float sv = w*t;
        if (sv > best){ best = sv; bi = c.x; }
        else if (sv == best && c.x < bi) bi = c.x;
      }
      c = nx;
    }
    // finalize (no cross-lane reduction needed)
    float bnd = (n == hv0) ? 0.f : 100.f;
    int deg = s1 - s0;
    float cntf = (float)(deg + 1);
#define FIN(cc, rc, S1c, S2c, Mc, mc) { \
      float mxv, mnv; \
      if (deg > 0){ \
        float em = (rc >= 0.f) ? rc*Mc : rc*mc; \
        float en = (rc >= 0.f) ? rc*mc : rc*Mc; \
        mxv = fmaxf(em, bnd); mnv = fminf(en, bnd); \
      } else { mxv = bnd; mnv = bnd; } \
      float meanv = (rc*S1c + bnd) / cntf; \
      float sq    = (rc*rc*S2c + bnd*bnd) / cntf; \
      float sdv   = sqrtf(fmaxf(sq - meanv*meanv, 1e-6f)); \
      int d = quad*4 + cc; \
      sh[(d*4+0)*33 + nl] = meanv; \
      sh[(d*4+1)*33 + nl] = mxv; \
      sh[(d*4+2)*33 + nl] = mnv; \
      sh[(d*4+3)*33 + nl] = sdv; }
    FIN(0, r4.x, S10, S20, M0, m0)
    FIN(1, r4.y, S11, S21, M1, m1)
    FIN(2, r4.z, S12, S22, M2, m2)
    FIN(3, r4.w, S13, S23, M3, m3)
#undef FIN
    if (PRED && valid && quad == 0){
      float ss = (n == hv0) ? 0.f : 3200.f;   // boundary self-loop row sum, w=1
      if (ss > best){ best = ss; bi = n; }
      else if (ss == best && n < bi) bi = n;
      pred_out[n] = (float)bi;
    }
  }
  __syncthreads();

  // ---- phase 2: linear ----
  {
    const float* Wl = lin_W + (size_t)l * 13312;   // 416*32
    int lane = tid & 63;
    int j0 = __builtin_amdgcn_readfirstlane((tid >> 6) * 8);  // 0,8,16,24
    if (lane < 32){
      int n0 = base + lane;
      int n = (n0 < NN) ? n0 : NN-1;
      float sc = scale_arr[n], iv = inv_arr[n];
      float acc[8];
      #pragma unroll
      for (int j = 0; j < 8; ++j) acc[j] = lin_b[l*32 + j0 + j];

      for (int k = 0; k < 32; ++k){
        float xv = hT[k*NN + n];
        const float* wr = Wl + k*32 + j0;
        #pragma unroll
        for (int j = 0; j < 8; ++j) acc[j] += xv * wr[j];
      }
      for (int kp = 0; kp < 128; ++kp){
        float f = sh[kp*33 + lane];
        int d = kp >> 2, c = kp & 3;
        const float* wr = Wl + (32 + d*12 + c*3)*32 + j0;
        float f1 = f*sc, f2 = f*iv;
        #pragma unroll
        for (int j = 0; j < 8; ++j)
          acc[j] += f*wr[j] + f1*wr[32+j] + f2*wr[64+j];
      }

      if (n0 < NN){
        #pragma unroll
        for (int j = 0; j < 8; ++j){
          float v = fmaxf(acc[j], 0.f);
          h_next[n0*32 + j0 + j] = v;
          hT_next[(j0+j)*NN + n0] = v;
        }
      }
    }
  }
}

// ---------------- final MLP ----------------
__global__ __launch_bounds__(256) void k_mlp(const float* __restrict__ hT,
                                             const float* __restrict__ qc,
                                             const float* __restrict__ W1,
                                             const float* __restrict__ W2,
                                             const float* __restrict__ b2,
                                             float* __restrict__ out_score){
  int n0 = blockIdx.x*256 + threadIdx.x;
  int n = (n0 < NN) ? n0 : NN-1;
  float acc[64];
  #pragma unroll
  for (int j = 0; j < 64; ++j) acc[j] = qc[j];
  for (int k = 0; k < 32; ++k){
    float xv = hT[k*NN + n];
    const float* wr = W1 + k*64;
    #pragma unroll
    for (int j = 0; j < 64; ++j) acc[j] += xv * wr[j];
  }
  float s = b2[0];
  #pragma unroll
  for (int j = 0; j < 64; ++j) s += fmaxf(acc[j], 0.f) * W2[j];
  if (n0 < NN) out_score[n0] = s;
}

// ---------------- host launch ----------------
extern "C" void kernel_launch(void* const* d_in, const int* in_sizes, int n_in,
                              void* d_out, int out_size, void* d_ws, size_t ws_size,
                              hipStream_t stream){
  const int*   node_in  = (const int*)d_in[0];
  const int*   node_out = (const int*)d_in[1];
  const float* ew       = (const float*)d_in[2];
  const int*   hidx     = (const int*)d_in[3];
  const float* qw       = (const float*)d_in[4];
  const float* rel_W    = (const float*)d_in[5];
  const float* rel_b    = (const float*)d_in[6];
  const float* lin_W    = (const float*)d_in[7];
  const float* lin_b    = (const float*)d_in[8];
  const float* W1       = (const float*)d_in[9];
  const float* b1       = (const float*)d_in[10];
  const float* W2       = (const float*)d_in[11];
  const float* b2       = (const float*)d_in[12];
  float* out_score = (float*)d_out;
  float* out_pred  = out_score + NN;

  char* w = (char*)d_ws;
  size_t off = 0;
  auto take = [&](size_t bytes)->char*{
    char* p = w + off;
    off = (off + bytes + 255) & ~(size_t)255;
    return p;
  };
  double* deg_pack = (double*)take((size_t)NN*8 + 64*4);
  float*  logsum   = (float*)(deg_pack + NN);
  int*   row_start = (int*)take((size_t)(NN+1)*4);
  int*   cursor    = (int*)take((size_t)NN*4);
  int*   partials  = (int*)take(256*4);
  float* rel6      = (float*)take(192*4);
  float* qc        = (float*)take(64*4);
  float* scale_arr = (float*)take((size_t)NN*4);
  float* inv_arr   = (float*)take((size_t)NN*4);
  float* tdot      = (float*)take((size_t)NN*4);
  int2*  csr       = (int2*)take((size_t)(EE+32)*8);
  float* h_a       = (float*)take((size_t)NN*32*4);
  float* hT_a      = (float*)take((size_t)NN*32*4);
  float* h_b       = (float*)take((size_t)NN*32*4);
  float* hT_b      = (float*)take((size_t)NN*32*4);

  int zc = 2*NN + 64;   // N doubles == 2N floats, + logsum block
  int nb = (NN + 255) / 256;   // 196
  int nlb = (NN + 31) / 32;    // 1563
  k_zero   <<<(zc+255)/256, 256, 0, stream>>>((float*)deg_pack, zc);
  k_hist   <<<(EE+255)/256, 256, 0, stream>>>(node_out, ew, deg_pack);
  k_logsum <<<nb, 256, 0, stream>>>(deg_pack, logsum);
  k_scan1  <<<nb, 256, 0, stream>>>(deg_pack, partials);
  k_scan2  <<<1, 256, 0, stream>>>(partials, nb, row_start, csr);
  k_scan3  <<<nb, 256, 0, stream>>>(deg_pack, partials, row_start, cursor);
  k_fillcsr<<<(EE+255)/256, 256, 0, stream>>>(node_in, node_out, ew, cursor, csr);
  k_scales <<<nb, 256, 0, stream>>>(deg_pack, logsum, scale_arr, inv_arr);
  k_prep   <<<1, 256, 0, stream>>>(qw, rel_W, rel_b, W1, b1, rel6, qc);
  k_init_h <<<(NN*DD+255)/256, 256, 0, stream>>>(hidx, h_a, hT_a);

  float* hc = h_a;  float* hTc = hT_a;
  float* hn = h_b;  float* hTn = hT_b;
  for (int l = 0; l < 6; ++l){
    if (l == 5){
      k_dot<<<nb, 256, 0, stream>>>(hc, rel6, tdot);
      k_layer<true><<<nlb, 256, 0, stream>>>(hc, hTc, rel6, row_start, csr,
                                             hidx, tdot, lin_W, lin_b,
                                             scale_arr, inv_arr, hn, hTn,
                                             out_pred, l);
    } else {
      k_layer<false><<<nlb, 256, 0, stream>>>(hc, hTc, rel6, row_start, csr,
                                              hidx, tdot, lin_W, lin_b,
                                              scale_arr, inv_arr, hn, hTn,
                                              out_pred, l);
    }
    float* t1 = hc;  hc = hn;  hn = t1;
    float* t2 = hTc; hTc = hTn; hTn = t2;
  }
  k_mlp<<<nb, 256, 0, stream>>>(hTc, qc, W1, W2, b2, out_score);
}

// Round 11
// 558.911 us; speedup vs baseline: 1.3516x; 1.1244x over previous
//
#include <hip/hip_runtime.h>
#include <math.h>

#define NN 50000
#define EE 800000
#define DD 32

// deg packing: one double atomic per edge carries both count and sum(w):
//   pack += 65536.0 + w   ->  count = floor(pack/65536), sumw = pack - 65536*count
__device__ __forceinline__ int pack_count(double p){ return (int)(p * (1.0/65536.0)); }
__device__ __forceinline__ float pack_sumw(double p){ return (float)(p - 65536.0 * (double)pack_count(p)); }

// ---------------- setup kernels ----------------

__global__ __launch_bounds__(256) void k_zero(float* p, int count){
  int i = blockIdx.x*256 + threadIdx.x;
  if (i < count) p[i] = 0.f;
}

__global__ __launch_bounds__(256) void k_hist(const int* __restrict__ node_out,
                                              const float* __restrict__ ew,
                                              double* __restrict__ deg_pack){
  int e = blockIdx.x*256 + threadIdx.x;
  if (e < EE){
    int o = node_out[e];
    atomicAdd(&deg_pack[o], 65536.0 + (double)ew[e]);
  }
}

__global__ __launch_bounds__(256) void k_logsum(const double* __restrict__ deg_pack,
                                                float* __restrict__ logsum){
  __shared__ float sd[256];
  int t = threadIdx.x; int n = blockIdx.x*256 + t;
  float v = 0.f;
  if (n < NN) v = logf(pack_sumw(deg_pack[n]) + 1.f);
  sd[t] = v; __syncthreads();
  for (int off = 128; off > 0; off >>= 1){
    if (t < off) sd[t] += sd[t+off];
    __syncthreads();
  }
  if (t == 0) atomicAdd(logsum, sd[0]);
}

__global__ __launch_bounds__(256) void k_scan1(const double* __restrict__ deg_pack,
                                               int* __restrict__ partials){
  __shared__ int sd[256];
  int t = threadIdx.x; int n = blockIdx.x*256 + t;
  sd[t] = (n < NN) ? pack_count(deg_pack[n]) : 0; __syncthreads();
  for (int off = 128; off > 0; off >>= 1){
    if (t < off) sd[t] += sd[t+off];
    __syncthreads();
  }
  if (t == 0) partials[blockIdx.x] = sd[0];
}

__global__ __launch_bounds__(256) void k_scan2(int* __restrict__ partials, int nb,
                                               int* __restrict__ row_start,
                                               int2* __restrict__ csr){
  __shared__ int sd[256];
  int t = threadIdx.x;
  int v = (t < nb) ? partials[t] : 0;
  sd[t] = v; __syncthreads();
  for (int off = 1; off < 256; off <<= 1){
    int x = (t >= off) ? sd[t-off] : 0;
    __syncthreads();
    sd[t] += x;
    __syncthreads();
  }
  if (t < nb) partials[t] = sd[t] - v;   // exclusive
  if (t == 0) row_start[NN] = EE;
  if (t < 32) csr[EE + t] = make_int2(0, 0);   // zero the pad tail (re-poisoned each call)
}

__global__ __launch_bounds__(256) void k_scan3(const double* __restrict__ deg_pack,
                                               const int* __restrict__ partials,
                                               int* __restrict__ row_start,
                                               int* __restrict__ cursor){
  __shared__ int sd[256];
  int t = threadIdx.x; int n = blockIdx.x*256 + t;
  int v = (n < NN) ? pack_count(deg_pack[n]) : 0;
  sd[t] = v; __syncthreads();
  for (int off = 1; off < 256; off <<= 1){
    int x = (t >= off) ? sd[t-off] : 0;
    __syncthreads();
    sd[t] += x;
    __syncthreads();
  }
  if (n < NN){
    int rs = partials[blockIdx.x] + sd[t] - v;  // exclusive
    row_start[n] = rs; cursor[n] = rs;
  }
}

__global__ __launch_bounds__(256) void k_fillcsr(const int* __restrict__ node_in,
                                                 const int* __restrict__ node_out,
                                                 const float* __restrict__ ew,
                                                 int* __restrict__ cursor,
                                                 int2* __restrict__ csr){
  int e = blockIdx.x*256 + threadIdx.x;
  if (e < EE){
    int o = node_out[e];
    int pos = atomicAdd(&cursor[o], 1);
    int2 v; v.x = node_in[e]; v.y = __float_as_int(ew[e]);
    csr[pos] = v;
  }
}

__global__ __launch_bounds__(256) void k_scales(const double* __restrict__ deg_pack,
                                                const float* __restrict__ logsum,
                                                float* __restrict__ scale_arr,
                                                float* __restrict__ inv_arr){
  int n = blockIdx.x*256 + threadIdx.x;
  if (n < NN){
    float mean = *logsum / (float)NN;
    float s = logf(pack_sumw(deg_pack[n]) + 1.f) / mean;
    scale_arr[n] = s;
    inv_arr[n]   = 1.f / fmaxf(s, 0.01f);
  }
}

// rel_input per layer (6x32) and query-part of final MLP (64)
__global__ __launch_bounds__(256) void k_prep(const float* __restrict__ qw,
                                              const float* __restrict__ rel_W,
                                              const float* __restrict__ rel_b,
                                              const float* __restrict__ W1,
                                              const float* __restrict__ b1,
                                              float* __restrict__ rel6,
                                              float* __restrict__ qc){
  int t = threadIdx.x;
  if (t < 192){
    int l = t >> 5, j = t & 31;
    float s = rel_b[t];
    for (int d = 0; d < 32; ++d) s += qw[d] * rel_W[l*1024 + d*32 + j];
    rel6[t] = s;
  } else if (t < 256){
    int j = t - 192;
    float s = b1[j];
    for (int k = 0; k < 32; ++k) s += qw[k] * W1[(32+k)*64 + j];
    qc[j] = s;
  }
}

__global__ __launch_bounds__(256) void k_init_h(const int* __restrict__ hidx,
                                                float* __restrict__ h,
                                                float* __restrict__ hT){
  int i = blockIdx.x*256 + threadIdx.x;
  int hv = *hidx;
  if (i < NN*DD){
    h[i]  = ((i >> 5) == hv) ? 0.f : 100.f;   // row-major: n = i/32
    int n2 = i % NN;                           // transposed: n = i % N
    hT[i] = (n2 == hv) ? 0.f : 100.f;
  }
}

// t[n] = dot(h[n], rel_layer5) for msg_score
__global__ __launch_bounds__(256) void k_dot(const float* __restrict__ h,
                                             const float* __restrict__ rel6,
                                             float* __restrict__ tdot){
  int n0 = blockIdx.x*256 + threadIdx.x;
  int n = (n0 < NN) ? n0 : NN-1;
  const float* relr = rel6 + 5*32;
  float s = 0.f;
  #pragma unroll
  for (int d = 0; d < 32; ++d) s += h[n*32 + d] * relr[d];
  if (n0 < NN) tdot[n0] = s;
}

// ---------------- fused per-layer kernel ----------------
// Block = 64 nodes, 256 threads. Combines R10's phase-1 (group-per-node:
// zero shuffles, accumulators node-reduced by construction) with R4-R6's
// phase-2 geometry (64 nodes node-per-lane over ALL 64 lanes, j-split with
// wave-uniform W -> s_load; R10's 32-node version idled half the lanes on
// the instruction-dominant linear).
// Phase 1: 32 groups of 8 lanes; group g handles nodes base+2g, base+2g+1
//   sequentially. Edge loop unrolled x2: two independent h dwordx4 gathers
//   in flight, csr prefetched 2 ahead (rotates only 2 int2). lane quad=tid&7
//   covers dims quad*4..+3 via float4. No tail masking: exact loop bounds,
//   guarded single-edge tail. PRED: all 8 lanes redundantly compute best/bi
//   (broadcast loads), per-edge score w*tdot[src] bit-identical to prior
//   rounds -> tie semantics preserved.
// LDS sh[128*65] = 33.3 KB: phase-2 reads sh[kp*65+lane] conflict-free.
// Grid 782 (~3 blocks/CU, grid-bound occupancy) -> launch_bounds(256,4).
template<bool PRED>
__global__ __launch_bounds__(256, 4) void k_layer(const float* __restrict__ h,
                                               const float* __restrict__ hT,
                                               const float* __restrict__ rel6,
                                               const int* __restrict__ row_start,
                                               const int2* __restrict__ csr,
                                               const int* __restrict__ hidx,
                                               const float* __restrict__ tdot,
                                               const float* __restrict__ lin_W,
                                               const float* __restrict__ lin_b,
                                               const float* __restrict__ scale_arr,
                                               const float* __restrict__ inv_arr,
                                               float* __restrict__ h_next,
                                               float* __restrict__ hT_next,
                                               float* __restrict__ pred_out,
                                               int l){
  __shared__ float sh[128*65];
  int tid = threadIdx.x;
  int base = blockIdx.x * 64;
  int hv0 = *hidx;

  // ---- phase 1: aggregation (one 8-lane group per node, 2 nodes/group) ----
  {
    int g    = tid >> 3;     // group 0..31
    int quad = tid & 7;      // dims quad*4..+3
    float4 r4 = ((const float4*)(rel6 + l*32))[quad];
    for (int sub = 0; sub < 2; ++sub){
      int nl = g*2 + sub;
      int n0 = base + nl;
      bool valid = n0 < NN;
      int n = valid ? n0 : NN-1;
      int s0 = row_start[n], s1 = row_start[n+1];
      float S10=0.f,S11=0.f,S12=0.f,S13=0.f;
      float S20=0.f,S21=0.f,S22=0.f,S23=0.f;
      float M0=-INFINITY,M1=-INFINITY,M2=-INFINITY,M3=-INFINITY;
      float m0=INFINITY,m1=INFINITY,m2=INFINITY,m3=INFINITY;
      float best=-INFINITY; int bi=NN;

#define ACC1(C, A, T) { \
      float w = __int_as_float(C.y); \
      float p0=w*A.x, p1=w*A.y, p2=w*A.z, p3=w*A.w; \
      S10+=p0; S11+=p1; S12+=p2; S13+=p3; \
      S20+=p0*A.x; S21+=p1*A.y; S22+=p2*A.z; S23+=p3*A.w; \
      M0=fmaxf(M0,p0); M1=fmaxf(M1,p1); M2=fmaxf(M2,p2); M3=fmaxf(M3,p3); \
      m0=fminf(m0,p0); m1=fminf(m1,p1); m2=fminf(m2,p2); m3=fminf(m3,p3); \
      if (PRED){ \
        float sv = w*T; \
        if (sv > best){ best = sv; bi = C.x; } \
        else if (sv == best && C.x < bi) bi = C.x; \
      } }

      int2 cA = csr[s0];       // pad covers s0==EE
      int2 cB = csr[s0+1];
      int e = s0;
      for (; e + 2 <= s1; e += 2){
        const float4* hA = (const float4*)(h + cA.x*32);
        const float4* hB = (const float4*)(h + cB.x*32);
        float4 a = hA[quad];
        float4 b = hB[quad];
        float tA=0.f, tB=0.f;
        if (PRED){ tA = tdot[cA.x]; tB = tdot[cB.x]; }
        int2 nA = csr[e+2];    // may cross into next row / pad: only used if
        int2 nB = csr[e+3];    // it is a real edge of this row (loop/tail guards)
        ACC1(cA, a, tA)
        ACC1(cB, b, tB)
        cA = nA; cB = nB;
      }
      if (e < s1){             // odd tail: cA holds csr[e]
        const float4* hA = (const float4*)(h + cA.x*32);
        float4 a = hA[quad];
        float tA = 0.f;
        if (PRED) tA = tdot[cA.x];
        ACC1(cA, a, tA)
      }
#undef ACC1

      // finalize (no cross-lane reduction needed)
      float bnd = (n == hv0) ? 0.f : 100.f;
      int deg = s1 - s0;
      float cntf = (float)(deg + 1);
#define FIN(cc, rc, S1c, S2c, Mc, mc) { \
      float mxv, mnv; \
      if (deg > 0){ \
        float em = (rc >= 0.f) ? rc*Mc : rc*mc; \
        float en = (rc >= 0.f) ? rc*mc : rc*Mc; \
        mxv = fmaxf(em, bnd); mnv = fminf(en, bnd); \
      } else { mxv = bnd; mnv = bnd; } \
      float meanv = (rc*S1c + bnd) / cntf; \
      float sq    = (rc*rc*S2c + bnd*bnd) / cntf; \
      float sdv   = sqrtf(fmaxf(sq - meanv*meanv, 1e-6f)); \
      int d = quad*4 + cc; \
      sh[(d*4+0)*65 + nl] = meanv; \
      sh[(d*4+1)*65 + nl] = mxv; \
      sh[(d*4+2)*65 + nl] = mnv; \
      sh[(d*4+3)*65 + nl] = sdv; }
      FIN(0, r4.x, S10, S20, M0, m0)
      FIN(1, r4.y, S11, S21, M1, m1)
      FIN(2, r4.z, S12, S22, M2, m2)
      FIN(3, r4.w, S13, S23, M3, m3)
#undef FIN
      if (PRED && valid && quad == 0){
        float ss = (n == hv0) ? 0.f : 3200.f;   // boundary self-loop row sum, w=1
        if (ss > best){ best = ss; bi = n; }
        else if (ss == best && n < bi) bi = n;
        pred_out[n] = (float)bi;
      }
    }
  }
  __syncthreads();

  // ---- phase 2: linear (all 64 lanes; j-split, s_load W) ----
  {
    const float* Wl = lin_W + (size_t)l * 13312;   // 416*32
    int lane = tid & 63;
    int j0 = __builtin_amdgcn_readfirstlane((tid >> 6) * 8);  // 0,8,16,24
    int n0 = base + lane;
    int n = (n0 < NN) ? n0 : NN-1;
    float sc = scale_arr[n], iv = inv_arr[n];
    float acc[8];
    #pragma unroll
    for (int j = 0; j < 8; ++j) acc[j] = lin_b[l*32 + j0 + j];

    for (int k = 0; k < 32; ++k){
      float xv = hT[k*NN + n];
      const float* wr = Wl + k*32 + j0;
      #pragma unroll
      for (int j = 0; j < 8; ++j) acc[j] += xv * wr[j];
    }
    for (int kp = 0; kp < 128; ++kp){
      float f = sh[kp*65 + lane];
      int d = kp >> 2, c = kp & 3;
      const float* wr = Wl + (32 + d*12 + c*3)*32 + j0;
      float f1 = f*sc, f2 = f*iv;
      #pragma unroll
      for (int j = 0; j < 8; ++j)
        acc[j] += f*wr[j] + f1*wr[32+j] + f2*wr[64+j];
    }

    if (n0 < NN){
      #pragma unroll
      for (int j = 0; j < 8; ++j){
        float v = fmaxf(acc[j], 0.f);
        h_next[n0*32 + j0 + j] = v;
        hT_next[(j0+j)*NN + n0] = v;
      }
    }
  }
}

// ---------------- final MLP ----------------
__global__ __launch_bounds__(256) void k_mlp(const float* __restrict__ hT,
                                             const float* __restrict__ qc,
                                             const float* __restrict__ W1,
                                             const float* __restrict__ W2,
                                             const float* __restrict__ b2,
                                             float* __restrict__ out_score){
  int n0 = blockIdx.x*256 + threadIdx.x;
  int n = (n0 < NN) ? n0 : NN-1;
  float acc[64];
  #pragma unroll
  for (int j = 0; j < 64; ++j) acc[j] = qc[j];
  for (int k = 0; k < 32; ++k){
    float xv = hT[k*NN + n];
    const float* wr = W1 + k*64;
    #pragma unroll
    for (int j = 0; j < 64; ++j) acc[j] += xv * wr[j];
  }
  float s = b2[0];
  #pragma unroll
  for (int j = 0; j < 64; ++j) s += fmaxf(acc[j], 0.f) * W2[j];
  if (n0 < NN) out_score[n0] = s;
}

// ---------------- host launch ----------------
extern "C" void kernel_launch(void* const* d_in, const int* in_sizes, int n_in,
                              void* d_out, int out_size, void* d_ws, size_t ws_size,
                              hipStream_t stream){
  const int*   node_in  = (const int*)d_in[0];
  const int*   node_out = (const int*)d_in[1];
  const float* ew       = (const float*)d_in[2];
  const int*   hidx     = (const int*)d_in[3];
  const float* qw       = (const float*)d_in[4];
  const float* rel_W    = (const float*)d_in[5];
  const float* rel_b    = (const float*)d_in[6];
  const float* lin_W    = (const float*)d_in[7];
  const float* lin_b    = (const float*)d_in[8];
  const float* W1       = (const float*)d_in[9];
  const float* b1       = (const float*)d_in[10];
  const float* W2       = (const float*)d_in[11];
  const float* b2       = (const float*)d_in[12];
  float* out_score = (float*)d_out;
  float* out_pred  = out_score + NN;

  char* w = (char*)d_ws;
  size_t off = 0;
  auto take = [&](size_t bytes)->char*{
    char* p = w + off;
    off = (off + bytes + 255) & ~(size_t)255;
    return p;
  };
  double* deg_pack = (double*)take((size_t)NN*8 + 64*4);
  float*  logsum   = (float*)(deg_pack + NN);
  int*   row_start = (int*)take((size_t)(NN+1)*4);
  int*   cursor    = (int*)take((size_t)NN*4);
  int*   partials  = (int*)take(256*4);
  float* rel6      = (float*)take(192*4);
  float* qc        = (float*)take(64*4);
  float* scale_arr = (float*)take((size_t)NN*4);
  float* inv_arr   = (float*)take((size_t)NN*4);
  float* tdot      = (float*)take((size_t)NN*4);
  int2*  csr       = (int2*)take((size_t)(EE+32)*8);
  float* h_a       = (float*)take((size_t)NN*32*4);
  float* hT_a      = (float*)take((size_t)NN*32*4);
  float* h_b       = (float*)take((size_t)NN*32*4);
  float* hT_b      = (float*)take((size_t)NN*32*4);

  int zc = 2*NN + 64;   // N doubles == 2N floats, + logsum block
  int nb = (NN + 255) / 256;   // 196
  int nlb = (NN + 63) / 64;    // 782
  k_zero   <<<(zc+255)/256, 256, 0, stream>>>((float*)deg_pack, zc);
  k_hist   <<<(EE+255)/256, 256, 0, stream>>>(node_out, ew, deg_pack);
  k_logsum <<<nb, 256, 0, stream>>>(deg_pack, logsum);
  k_scan1  <<<nb, 256, 0, stream>>>(deg_pack, partials);
  k_scan2  <<<1, 256, 0, stream>>>(partials, nb, row_start, csr);
  k_scan3  <<<nb, 256, 0, stream>>>(deg_pack, partials, row_start, cursor);
  k_fillcsr<<<(EE+255)/256, 256, 0, stream>>>(node_in, node_out, ew, cursor, csr);
  k_scales <<<nb, 256, 0, stream>>>(deg_pack, logsum, scale_arr, inv_arr);
  k_prep   <<<1, 256, 0, stream>>>(qw, rel_W, rel_b, W1, b1, rel6, qc);
  k_init_h <<<(NN*DD+255)/256, 256, 0, stream>>>(hidx, h_a, hT_a);

  float* hc = h_a;  float* hTc = hT_a;
  float* hn = h_b;  float* hTn = hT_b;
  for (int l = 0; l < 6; ++l){
    if (l == 5){
      k_dot<<<nb, 256, 0, stream>>>(hc, rel6, tdot);
      k_layer<true><<<nlb, 256, 0, stream>>>(hc, hTc, rel6, row_start, csr,
                                             hidx, tdot, lin_W, lin_b,
                                             scale_arr, inv_arr, hn, hTn,
                                             out_pred, l);
    } else {
      k_layer<false><<<nlb, 256, 0, stream>>>(hc, hTc, rel6, row_start, csr,
                                              hidx, tdot, lin_W, lin_b,
                                              scale_arr, inv_arr, hn, hTn,
                                              out_pred, l);
    }
    float* t1 = hc;  hc = hn;  hn = t1;
    float* t2 = hTc; hTc = hTn; hTn = t2;
  }
  k_mlp<<<nb, 256, 0, stream>>>(hTc, qc, W1, W2, b2, out_score);
}

// Round 12
// 557.192 us; speedup vs baseline: 1.3558x; 1.0031x over previous
//
#include <hip/hip_runtime.h>
#include <math.h>

#define NN 50000
#define EE 800000
#define DD 32

// deg packing: one double atomic per edge carries both count and sum(w):
//   pack += 65536.0 + w   ->  count = floor(pack/65536), sumw = pack - 65536*count
__device__ __forceinline__ int pack_count(double p){ return (int)(p * (1.0/65536.0)); }
__device__ __forceinline__ float pack_sumw(double p){ return (float)(p - 65536.0 * (double)pack_count(p)); }

// ---------------- setup kernels ----------------

__global__ __launch_bounds__(256) void k_zero(float* p, int count){
  int i = blockIdx.x*256 + threadIdx.x;
  if (i < count) p[i] = 0.f;
}

__global__ __launch_bounds__(256) void k_hist(const int* __restrict__ node_out,
                                              const float* __restrict__ ew,
                                              double* __restrict__ deg_pack){
  int e = blockIdx.x*256 + threadIdx.x;
  if (e < EE){
    int o = node_out[e];
    atomicAdd(&deg_pack[o], 65536.0 + (double)ew[e]);
  }
}

__global__ __launch_bounds__(256) void k_logsum(const double* __restrict__ deg_pack,
                                                float* __restrict__ logsum){
  __shared__ float sd[256];
  int t = threadIdx.x; int n = blockIdx.x*256 + t;
  float v = 0.f;
  if (n < NN) v = logf(pack_sumw(deg_pack[n]) + 1.f);
  sd[t] = v; __syncthreads();
  for (int off = 128; off > 0; off >>= 1){
    if (t < off) sd[t] += sd[t+off];
    __syncthreads();
  }
  if (t == 0) atomicAdd(logsum, sd[0]);
}

__global__ __launch_bounds__(256) void k_scan1(const double* __restrict__ deg_pack,
                                               int* __restrict__ partials){
  __shared__ int sd[256];
  int t = threadIdx.x; int n = blockIdx.x*256 + t;
  sd[t] = (n < NN) ? pack_count(deg_pack[n]) : 0; __syncthreads();
  for (int off = 128; off > 0; off >>= 1){
    if (t < off) sd[t] += sd[t+off];
    __syncthreads();
  }
  if (t == 0) partials[blockIdx.x] = sd[0];
}

__global__ __launch_bounds__(256) void k_scan2(int* __restrict__ partials, int nb,
                                               int* __restrict__ row_start,
                                               int2* __restrict__ csr){
  __shared__ int sd[256];
  int t = threadIdx.x;
  int v = (t < nb) ? partials[t] : 0;
  sd[t] = v; __syncthreads();
  for (int off = 1; off < 256; off <<= 1){
    int x = (t >= off) ? sd[t-off] : 0;
    __syncthreads();
    sd[t] += x;
    __syncthreads();
  }
  if (t < nb) partials[t] = sd[t] - v;   // exclusive
  if (t == 0) row_start[NN] = EE;
  if (t < 32) csr[EE + t] = make_int2(0, 0);   // zero the pad tail (re-poisoned each call)
}

__global__ __launch_bounds__(256) void k_scan3(const double* __restrict__ deg_pack,
                                               const int* __restrict__ partials,
                                               int* __restrict__ row_start,
                                               int* __restrict__ cursor){
  __shared__ int sd[256];
  int t = threadIdx.x; int n = blockIdx.x*256 + t;
  int v = (n < NN) ? pack_count(deg_pack[n]) : 0;
  sd[t] = v; __syncthreads();
  for (int off = 1; off < 256; off <<= 1){
    int x = (t >= off) ? sd[t-off] : 0;
    __syncthreads();
    sd[t] += x;
    __syncthreads();
  }
  if (n < NN){
    int rs = partials[blockIdx.x] + sd[t] - v;  // exclusive
    row_start[n] = rs; cursor[n] = rs;
  }
}

__global__ __launch_bounds__(256) void k_fillcsr(const int* __restrict__ node_in,
                                                 const int* __restrict__ node_out,
                                                 const float* __restrict__ ew,
                                                 int* __restrict__ cursor,
                                                 int2* __restrict__ csr){
  int e = blockIdx.x*256 + threadIdx.x;
  if (e < EE){
    int o = node_out[e];
    int pos = atomicAdd(&cursor[o], 1);
    int2 v; v.x = node_in[e]; v.y = __float_as_int(ew[e]);
    csr[pos] = v;
  }
}

__global__ __launch_bounds__(256) void k_scales(const double* __restrict__ deg_pack,
                                                const float* __restrict__ logsum,
                                                float* __restrict__ scale_arr,
                                                float* __restrict__ inv_arr){
  int n = blockIdx.x*256 + threadIdx.x;
  if (n < NN){
    float mean = *logsum / (float)NN;
    float s = logf(pack_sumw(deg_pack[n]) + 1.f) / mean;
    scale_arr[n] = s;
    inv_arr[n]   = 1.f / fmaxf(s, 0.01f);
  }
}

// rel_input per layer (6x32) and query-part of final MLP (64)
__global__ __launch_bounds__(256) void k_prep(const float* __restrict__ qw,
                                              const float* __restrict__ rel_W,
                                              const float* __restrict__ rel_b,
                                              const float* __restrict__ W1,
                                              const float* __restrict__ b1,
                                              float* __restrict__ rel6,
                                              float* __restrict__ qc){
  int t = threadIdx.x;
  if (t < 192){
    int l = t >> 5, j = t & 31;
    float s = rel_b[t];
    for (int d = 0; d < 32; ++d) s += qw[d] * rel_W[l*1024 + d*32 + j];
    rel6[t] = s;
  } else if (t < 256){
    int j = t - 192;
    float s = b1[j];
    for (int k = 0; k < 32; ++k) s += qw[k] * W1[(32+k)*64 + j];
    qc[j] = s;
  }
}

__global__ __launch_bounds__(256) void k_init_h(const int* __restrict__ hidx,
                                                float* __restrict__ h,
                                                float* __restrict__ hT){
  int i = blockIdx.x*256 + threadIdx.x;
  int hv = *hidx;
  if (i < NN*DD){
    h[i]  = ((i >> 5) == hv) ? 0.f : 100.f;   // row-major: n = i/32
    int n2 = i % NN;                           // transposed: n = i % N
    hT[i] = (n2 == hv) ? 0.f : 100.f;
  }
}

// t[n] = dot(h[n], rel_layer5) for msg_score
__global__ __launch_bounds__(256) void k_dot(const float* __restrict__ h,
                                             const float* __restrict__ rel6,
                                             float* __restrict__ tdot){
  int n0 = blockIdx.x*256 + threadIdx.x;
  int n = (n0 < NN) ? n0 : NN-1;
  const float* relr = rel6 + 5*32;
  float s = 0.f;
  #pragma unroll
  for (int d = 0; d < 32; ++d) s += h[n*32 + d] * relr[d];
  if (n0 < NN) tdot[n0] = s;
}

// ---------------- fused per-layer kernel ----------------
// Block = 64 nodes, 512 threads = 8 waves. R11 post-mortem: at 256 threads
// the grid (782 blocks ~ 3/CU) capped occupancy at 12 waves/CU and phase-1
// gather latency was exposed (VALUBusy 29%). 512-thread blocks keep the same
// node mapping + phase-2 s_load structure but double resident waves:
// 3 blocks/CU x 8 waves = 24 waves/CU (75% ceiling). LDS 33.3 KB still
// allows 4 blocks/CU. launch_bounds(512,6): 6 waves/SIMD -> VGPR cap ~85.
// Phase 1: 64 groups of 8 lanes, ONE node per group (no sub-loop; zero
//   shuffles, accumulators node-reduced by construction). Edge loop x2
//   unrolled, two independent h dwordx4 gathers in flight, csr prefetched.
// Phase 2: 8 waves, wave w covers j0 = w*4 (wave-uniform -> s_load), 4 j's
//   per lane, node = lane (64 lanes).
template<bool PRED>
__global__ __launch_bounds__(512, 6) void k_layer(const float* __restrict__ h,
                                               const float* __restrict__ hT,
                                               const float* __restrict__ rel6,
                                               const int* __restrict__ row_start,
                                               const int2* __restrict__ csr,
                                               const int* __restrict__ hidx,
                                               const float* __restrict__ tdot,
                                               const float* __restrict__ lin_W,
                                               const float* __restrict__ lin_b,
                                               const float* __restrict__ scale_arr,
                                               const float* __restrict__ inv_arr,
                                               float* __restrict__ h_next,
                                               float* __restrict__ hT_next,
                                               float* __restrict__ pred_out,
                                               int l){
  __shared__ float sh[128*65];
  int tid = threadIdx.x;
  int base = blockIdx.x * 64;
  int hv0 = *hidx;

  // ---- phase 1: aggregation (one 8-lane group per node) ----
  {
    int nl   = tid >> 3;     // group = node index in block, 0..63
    int quad = tid & 7;      // dims quad*4..+3
    float4 r4 = ((const float4*)(rel6 + l*32))[quad];
    int n0 = base + nl;
    bool valid = n0 < NN;
    int n = valid ? n0 : NN-1;
    int s0 = row_start[n], s1 = row_start[n+1];
    float S10=0.f,S11=0.f,S12=0.f,S13=0.f;
    float S20=0.f,S21=0.f,S22=0.f,S23=0.f;
    float M0=-INFINITY,M1=-INFINITY,M2=-INFINITY,M3=-INFINITY;
    float m0=INFINITY,m1=INFINITY,m2=INFINITY,m3=INFINITY;
    float best=-INFINITY; int bi=NN;

#define ACC1(C, A, T) { \
    float w = __int_as_float(C.y); \
    float p0=w*A.x, p1=w*A.y, p2=w*A.z, p3=w*A.w; \
    S10+=p0; S11+=p1; S12+=p2; S13+=p3; \
    S20+=p0*A.x; S21+=p1*A.y; S22+=p2*A.z; S23+=p3*A.w; \
    M0=fmaxf(M0,p0); M1=fmaxf(M1,p1); M2=fmaxf(M2,p2); M3=fmaxf(M3,p3); \
    m0=fminf(m0,p0); m1=fminf(m1,p1); m2=fminf(m2,p2); m3=fminf(m3,p3); \
    if (PRED){ \
      float sv = w*T; \
      if (sv > best){ best = sv; bi = C.x; } \
      else if (sv == best && C.x < bi) bi = C.x; \
    } }

    int2 cA = csr[s0];       // pad covers s0==EE
    int2 cB = csr[s0+1];
    int e = s0;
    for (; e + 2 <= s1; e += 2){
      const float4* hA = (const float4*)(h + cA.x*32);
      const float4* hB = (const float4*)(h + cB.x*32);
      float4 a = hA[quad];
      float4 b = hB[quad];
      float tA=0.f, tB=0.f;
      if (PRED){ tA = tdot[cA.x]; tB = tdot[cB.x]; }
      int2 nA = csr[e+2];    // may cross into next row / pad: only consumed
      int2 nB = csr[e+3];    // if it is a real edge of this row
      ACC1(cA, a, tA)
      ACC1(cB, b, tB)
      cA = nA; cB = nB;
    }
    if (e < s1){             // odd tail: cA holds csr[e]
      const float4* hA = (const float4*)(h + cA.x*32);
      float4 a = hA[quad];
      float tA = 0.f;
      if (PRED) tA = tdot[cA.x];
      ACC1(cA, a, tA)
    }
#undef ACC1

    // finalize (no cross-lane reduction needed)
    float bnd = (n == hv0) ? 0.f : 100.f;
    int deg = s1 - s0;
    float cntf = (float)(deg + 1);
#define FIN(cc, rc, S1c, S2c, Mc, mc) { \
    float mxv, mnv; \
    if (deg > 0){ \
      float em = (rc >= 0.f) ? rc*Mc : rc*mc; \
      float en = (rc >= 0.f) ? rc*mc : rc*Mc; \
      mxv = fmaxf(em, bnd); mnv = fminf(en, bnd); \
    } else { mxv = bnd; mnv = bnd; } \
    float meanv = (rc*S1c + bnd) / cntf; \
    float sq    = (rc*rc*S2c + bnd*bnd) / cntf; \
    float sdv   = sqrtf(fmaxf(sq - meanv*meanv, 1e-6f)); \
    int d = quad*4 + cc; \
    sh[(d*4+0)*65 + nl] = meanv; \
    sh[(d*4+1)*65 + nl] = mxv; \
    sh[(d*4+2)*65 + nl] = mnv; \
    sh[(d*4+3)*65 + nl] = sdv; }
    FIN(0, r4.x, S10, S20, M0, m0)
    FIN(1, r4.y, S11, S21, M1, m1)
    FIN(2, r4.z, S12, S22, M2, m2)
    FIN(3, r4.w, S13, S23, M3, m3)
#undef FIN
    if (PRED && valid && quad == 0){
      float ss = (n == hv0) ? 0.f : 3200.f;   // boundary self-loop row sum, w=1
      if (ss > best){ best = ss; bi = n; }
      else if (ss == best && n < bi) bi = n;
      pred_out[n] = (float)bi;
    }
  }
  __syncthreads();

  // ---- phase 2: linear (8 waves, wave w -> j0 = w*4; node = lane) ----
  {
    const float* Wl = lin_W + (size_t)l * 13312;   // 416*32
    int lane = tid & 63;
    int j0 = __builtin_amdgcn_readfirstlane((tid >> 6) * 4);  // 0,4,...,28
    int n0 = base + lane;
    int n = (n0 < NN) ? n0 : NN-1;
    float sc = scale_arr[n], iv = inv_arr[n];
    float acc[4];
    #pragma unroll
    for (int j = 0; j < 4; ++j) acc[j] = lin_b[l*32 + j0 + j];

    for (int k = 0; k < 32; ++k){
      float xv = hT[k*NN + n];
      const float* wr = Wl + k*32 + j0;
      #pragma unroll
      for (int j = 0; j < 4; ++j) acc[j] += xv * wr[j];
    }
    for (int kp = 0; kp < 128; ++kp){
      float f = sh[kp*65 + lane];
      int d = kp >> 2, c = kp & 3;
      const float* wr = Wl + (32 + d*12 + c*3)*32 + j0;
      float f1 = f*sc, f2 = f*iv;
      #pragma unroll
      for (int j = 0; j < 4; ++j)
        acc[j] += f*wr[j] + f1*wr[32+j] + f2*wr[64+j];
    }

    if (n0 < NN){
      #pragma unroll
      for (int j = 0; j < 4; ++j){
        float v = fmaxf(acc[j], 0.f);
        h_next[n0*32 + j0 + j] = v;
        hT_next[(j0+j)*NN + n0] = v;
      }
    }
  }
}

// ---------------- final MLP ----------------
__global__ __launch_bounds__(256) void k_mlp(const float* __restrict__ hT,
                                             const float* __restrict__ qc,
                                             const float* __restrict__ W1,
                                             const float* __restrict__ W2,
                                             const float* __restrict__ b2,
                                             float* __restrict__ out_score){
  int n0 = blockIdx.x*256 + threadIdx.x;
  int n = (n0 < NN) ? n0 : NN-1;
  float acc[64];
  #pragma unroll
  for (int j = 0; j < 64; ++j) acc[j] = qc[j];
  for (int k = 0; k < 32; ++k){
    float xv = hT[k*NN + n];
    const float* wr = W1 + k*64;
    #pragma unroll
    for (int j = 0; j < 64; ++j) acc[j] += xv * wr[j];
  }
  float s = b2[0];
  #pragma unroll
  for (int j = 0; j < 64; ++j) s += fmaxf(acc[j], 0.f) * W2[j];
  if (n0 < NN) out_score[n0] = s;
}

// ---------------- host launch ----------------
extern "C" void kernel_launch(void* const* d_in, const int* in_sizes, int n_in,
                              void* d_out, int out_size, void* d_ws, size_t ws_size,
                              hipStream_t stream){
  const int*   node_in  = (const int*)d_in[0];
  const int*   node_out = (const int*)d_in[1];
  const float* ew       = (const float*)d_in[2];
  const int*   hidx     = (const int*)d_in[3];
  const float* qw       = (const float*)d_in[4];
  const float* rel_W    = (const float*)d_in[5];
  const float* rel_b    = (const float*)d_in[6];
  const float* lin_W    = (const float*)d_in[7];
  const float* lin_b    = (const float*)d_in[8];
  const float* W1       = (const float*)d_in[9];
  const float* b1       = (const float*)d_in[10];
  const float* W2       = (const float*)d_in[11];
  const float* b2       = (const float*)d_in[12];
  float* out_score = (float*)d_out;
  float* out_pred  = out_score + NN;

  char* w = (char*)d_ws;
  size_t off = 0;
  auto take = [&](size_t bytes)->char*{
    char* p = w + off;
    off = (off + bytes + 255) & ~(size_t)255;
    return p;
  };
  double* deg_pack = (double*)take((size_t)NN*8 + 64*4);
  float*  logsum   = (float*)(deg_pack + NN);
  int*   row_start = (int*)take((size_t)(NN+1)*4);
  int*   cursor    = (int*)take((size_t)NN*4);
  int*   partials  = (int*)take(256*4);
  float* rel6      = (float*)take(192*4);
  float* qc        = (float*)take(64*4);
  float* scale_arr = (float*)take((size_t)NN*4);
  float* inv_arr   = (float*)take((size_t)NN*4);
  float* tdot      = (float*)take((size_t)NN*4);
  int2*  csr       = (int2*)take((size_t)(EE+32)*8);
  float* h_a       = (float*)take((size_t)NN*32*4);
  float* hT_a      = (float*)take((size_t)NN*32*4);
  float* h_b       = (float*)take((size_t)NN*32*4);
  float* hT_b      = (float*)take((size_t)NN*32*4);

  int zc = 2*NN + 64;   // N doubles == 2N floats, + logsum block
  int nb = (NN + 255) / 256;   // 196
  int nlb = (NN + 63) / 64;    // 782
  k_zero   <<<(zc+255)/256, 256, 0, stream>>>((float*)deg_pack, zc);
  k_hist   <<<(EE+255)/256, 256, 0, stream>>>(node_out, ew, deg_pack);
  k_logsum <<<nb, 256, 0, stream>>>(deg_pack, logsum);
  k_scan1  <<<nb, 256, 0, stream>>>(deg_pack, partials);
  k_scan2  <<<1, 256, 0, stream>>>(partials, nb, row_start, csr);
  k_scan3  <<<nb, 256, 0, stream>>>(deg_pack, partials, row_start, cursor);
  k_fillcsr<<<(EE+255)/256, 256, 0, stream>>>(node_in, node_out, ew, cursor, csr);
  k_scales <<<nb, 256, 0, stream>>>(deg_pack, logsum, scale_arr, inv_arr);
  k_prep   <<<1, 256, 0, stream>>>(qw, rel_W, rel_b, W1, b1, rel6, qc);
  k_init_h <<<(NN*DD+255)/256, 256, 0, stream>>>(hidx, h_a, hT_a);

  float* hc = h_a;  float* hTc = hT_a;
  float* hn = h_b;  float* hTn = hT_b;
  for (int l = 0; l < 6; ++l){
    if (l == 5){
      k_dot<<<nb, 256, 0, stream>>>(hc, rel6, tdot);
      k_layer<true><<<nlb, 512, 0, stream>>>(hc, hTc, rel6, row_start, csr,
                                             hidx, tdot, lin_W, lin_b,
                                             scale_arr, inv_arr, hn, hTn,
                                             out_pred, l);
    } else {
      k_layer<false><<<nlb, 512, 0, stream>>>(hc, hTc, rel6, row_start, csr,
                                              hidx, tdot, lin_W, lin_b,
                                              scale_arr, inv_arr, hn, hTn,
                                              out_pred, l);
    }
    float* t1 = hc;  hc = hn;  hn = t1;
    float* t2 = hTc; hTc = hTn; hTn = t2;
  }
  k_mlp<<<nb, 256, 0, stream>>>(hTc, qc, W1, W2, b2, out_score);
}

// Round 13
// 522.183 us; speedup vs baseline: 1.4467x; 1.0670x over previous
//
#include <hip/hip_runtime.h>
#include <math.h>

#define NN 50000
#define EE 800000
#define DD 32

typedef float v2f __attribute__((ext_vector_type(2)));

// deg packing: one double atomic per edge carries both count and sum(w):
//   pack += 65536.0 + w   ->  count = floor(pack/65536), sumw = pack - 65536*count
__device__ __forceinline__ int pack_count(double p){ return (int)(p * (1.0/65536.0)); }
__device__ __forceinline__ float pack_sumw(double p){ return (float)(p - 65536.0 * (double)pack_count(p)); }

// ---------------- setup kernels ----------------

__global__ __launch_bounds__(256) void k_zero(float* p, int count){
  int i = blockIdx.x*256 + threadIdx.x;
  if (i < count) p[i] = 0.f;
}

__global__ __launch_bounds__(256) void k_hist(const int* __restrict__ node_out,
                                              const float* __restrict__ ew,
                                              double* __restrict__ deg_pack){
  int e = blockIdx.x*256 + threadIdx.x;
  if (e < EE){
    int o = node_out[e];
    atomicAdd(&deg_pack[o], 65536.0 + (double)ew[e]);
  }
}

__global__ __launch_bounds__(256) void k_logsum(const double* __restrict__ deg_pack,
                                                float* __restrict__ logsum){
  __shared__ float sd[256];
  int t = threadIdx.x; int n = blockIdx.x*256 + t;
  float v = 0.f;
  if (n < NN) v = logf(pack_sumw(deg_pack[n]) + 1.f);
  sd[t] = v; __syncthreads();
  for (int off = 128; off > 0; off >>= 1){
    if (t < off) sd[t] += sd[t+off];
    __syncthreads();
  }
  if (t == 0) atomicAdd(logsum, sd[0]);
}

__global__ __launch_bounds__(256) void k_scan1(const double* __restrict__ deg_pack,
                                               int* __restrict__ partials){
  __shared__ int sd[256];
  int t = threadIdx.x; int n = blockIdx.x*256 + t;
  sd[t] = (n < NN) ? pack_count(deg_pack[n]) : 0; __syncthreads();
  for (int off = 128; off > 0; off >>= 1){
    if (t < off) sd[t] += sd[t+off];
    __syncthreads();
  }
  if (t == 0) partials[blockIdx.x] = sd[0];
}

__global__ __launch_bounds__(256) void k_scan2(int* __restrict__ partials, int nb,
                                               int* __restrict__ row_start,
                                               int2* __restrict__ csr){
  __shared__ int sd[256];
  int t = threadIdx.x;
  int v = (t < nb) ? partials[t] : 0;
  sd[t] = v; __syncthreads();
  for (int off = 1; off < 256; off <<= 1){
    int x = (t >= off) ? sd[t-off] : 0;
    __syncthreads();
    sd[t] += x;
    __syncthreads();
  }
  if (t < nb) partials[t] = sd[t] - v;   // exclusive
  if (t == 0) row_start[NN] = EE;
  if (t < 32) csr[EE + t] = make_int2(0, 0);   // zero the pad tail (re-poisoned each call)
}

__global__ __launch_bounds__(256) void k_scan3(const double* __restrict__ deg_pack,
                                               const int* __restrict__ partials,
                                               int* __restrict__ row_start,
                                               int* __restrict__ cursor){
  __shared__ int sd[256];
  int t = threadIdx.x; int n = blockIdx.x*256 + t;
  int v = (n < NN) ? pack_count(deg_pack[n]) : 0;
  sd[t] = v; __syncthreads();
  for (int off = 1; off < 256; off <<= 1){
    int x = (t >= off) ? sd[t-off] : 0;
    __syncthreads();
    sd[t] += x;
    __syncthreads();
  }
  if (n < NN){
    int rs = partials[blockIdx.x] + sd[t] - v;  // exclusive
    row_start[n] = rs; cursor[n] = rs;
  }
}

__global__ __launch_bounds__(256) void k_fillcsr(const int* __restrict__ node_in,
                                                 const int* __restrict__ node_out,
                                                 const float* __restrict__ ew,
                                                 int* __restrict__ cursor,
                                                 int2* __restrict__ csr){
  int e = blockIdx.x*256 + threadIdx.x;
  if (e < EE){
    int o = node_out[e];
    int pos = atomicAdd(&cursor[o], 1);
    int2 v; v.x = node_in[e]; v.y = __float_as_int(ew[e]);
    csr[pos] = v;
  }
}

__global__ __launch_bounds__(256) void k_scales(const double* __restrict__ deg_pack,
                                                const float* __restrict__ logsum,
                                                float* __restrict__ scale_arr,
                                                float* __restrict__ inv_arr){
  int n = blockIdx.x*256 + threadIdx.x;
  if (n < NN){
    float mean = *logsum / (float)NN;
    float s = logf(pack_sumw(deg_pack[n]) + 1.f) / mean;
    scale_arr[n] = s;
    inv_arr[n]   = 1.f / fmaxf(s, 0.01f);
  }
}

// rel_input per layer (6x32) and query-part of final MLP (64)
__global__ __launch_bounds__(256) void k_prep(const float* __restrict__ qw,
                                              const float* __restrict__ rel_W,
                                              const float* __restrict__ rel_b,
                                              const float* __restrict__ W1,
                                              const float* __restrict__ b1,
                                              float* __restrict__ rel6,
                                              float* __restrict__ qc){
  int t = threadIdx.x;
  if (t < 192){
    int l = t >> 5, j = t & 31;
    float s = rel_b[t];
    for (int d = 0; d < 32; ++d) s += qw[d] * rel_W[l*1024 + d*32 + j];
    rel6[t] = s;
  } else if (t < 256){
    int j = t - 192;
    float s = b1[j];
    for (int k = 0; k < 32; ++k) s += qw[k] * W1[(32+k)*64 + j];
    qc[j] = s;
  }
}

__global__ __launch_bounds__(256) void k_init_h(const int* __restrict__ hidx,
                                                float* __restrict__ h,
                                                float* __restrict__ hT){
  int i = blockIdx.x*256 + threadIdx.x;
  int hv = *hidx;
  if (i < NN*DD){
    h[i]  = ((i >> 5) == hv) ? 0.f : 100.f;   // row-major: n = i/32
    int n2 = i % NN;                           // transposed: n = i % N
    hT[i] = (n2 == hv) ? 0.f : 100.f;
  }
}

// t[n] = dot(h[n], rel_layer5) for msg_score
__global__ __launch_bounds__(256) void k_dot(const float* __restrict__ h,
                                             const float* __restrict__ rel6,
                                             float* __restrict__ tdot){
  int n0 = blockIdx.x*256 + threadIdx.x;
  int n = (n0 < NN) ? n0 : NN-1;
  const float* relr = rel6 + 5*32;
  float s = 0.f;
  #pragma unroll
  for (int d = 0; d < 32; ++d) s += h[n*32 + d] * relr[d];
  if (n0 < NN) tdot[n0] = s;
}

// ---------------- fused per-layer kernel ----------------
// Block = 64 nodes, 512 threads = 8 waves (R12 geometry).
// R12 post-mortem: k_layer plateaued ~69 us with VALU floor ~15 us -> the
// cost is exposed gather latency (h rows miss per-XCD L2 -> L3 ~500-900 cyc)
// with one wait per 2 edges, plus phase-2 at 1 FLOP/VALU-inst.
// This round: (1) phase-1 unroll-4 -- 4 independent h dwordx4 gathers in
// flight per group-step, csr prefetched 4 ahead (one waitcnt per 4 edges);
// accumulation order per node unchanged (bit-identical, PRED ties preserved).
// (2) phase-2 packed fp32 (ext_vector float2 -> v_pk_fma_f32) halves the
// linear-layer VALU instruction count.
template<bool PRED>
__global__ __launch_bounds__(512, 6) void k_layer(const float* __restrict__ h,
                                               const float* __restrict__ hT,
                                               const float* __restrict__ rel6,
                                               const int* __restrict__ row_start,
                                               const int2* __restrict__ csr,
                                               const int* __restrict__ hidx,
                                               const float* __restrict__ tdot,
                                               const float* __restrict__ lin_W,
                                               const float* __restrict__ lin_b,
                                               const float* __restrict__ scale_arr,
                                               const float* __restrict__ inv_arr,
                                               float* __restrict__ h_next,
                                               float* __restrict__ hT_next,
                                               float* __restrict__ pred_out,
                                               int l){
  __shared__ float sh[128*65];
  int tid = threadIdx.x;
  int base = blockIdx.x * 64;
  int hv0 = *hidx;

  // ---- phase 1: aggregation (one 8-lane group per node, unroll-4) ----
  {
    int nl   = tid >> 3;     // group = node index in block, 0..63
    int quad = tid & 7;      // dims quad*4..+3
    float4 r4 = ((const float4*)(rel6 + l*32))[quad];
    int n0 = base + nl;
    bool valid = n0 < NN;
    int n = valid ? n0 : NN-1;
    int s0 = row_start[n], s1 = row_start[n+1];
    float S10=0.f,S11=0.f,S12=0.f,S13=0.f;
    float S20=0.f,S21=0.f,S22=0.f,S23=0.f;
    float M0=-INFINITY,M1=-INFINITY,M2=-INFINITY,M3=-INFINITY;
    float m0=INFINITY,m1=INFINITY,m2=INFINITY,m3=INFINITY;
    float best=-INFINITY; int bi=NN;

#define ACC1(C, A, T) { \
    float w = __int_as_float(C.y); \
    float p0=w*A.x, p1=w*A.y, p2=w*A.z, p3=w*A.w; \
    S10+=p0; S11+=p1; S12+=p2; S13+=p3; \
    S20+=p0*A.x; S21+=p1*A.y; S22+=p2*A.z; S23+=p3*A.w; \
    M0=fmaxf(M0,p0); M1=fmaxf(M1,p1); M2=fmaxf(M2,p2); M3=fmaxf(M3,p3); \
    m0=fminf(m0,p0); m1=fminf(m1,p1); m2=fminf(m2,p2); m3=fminf(m3,p3); \
    if (PRED){ \
      float sv = w*T; \
      if (sv > best){ best = sv; bi = C.x; } \
      else if (sv == best && C.x < bi) bi = C.x; \
    } }

    // csr pipelined one 4-batch ahead (pad covers reads past s1/EE)
    int2 cA = csr[s0],   cB = csr[s0+1], cC = csr[s0+2], cD = csr[s0+3];
    int e = s0;
    for (; e + 4 <= s1; e += 4){
      float4 a = ((const float4*)(h + cA.x*32))[quad];
      float4 b = ((const float4*)(h + cB.x*32))[quad];
      float4 c4 = ((const float4*)(h + cC.x*32))[quad];
      float4 d4 = ((const float4*)(h + cD.x*32))[quad];
      float tA=0.f, tB=0.f, tC=0.f, tD=0.f;
      if (PRED){ tA = tdot[cA.x]; tB = tdot[cB.x]; tC = tdot[cC.x]; tD = tdot[cD.x]; }
      int2 nA = csr[e+4], nB = csr[e+5], nC = csr[e+6], nD = csr[e+7];
      ACC1(cA, a, tA)
      ACC1(cB, b, tB)
      ACC1(cC, c4, tC)
      ACC1(cD, d4, tD)
      cA = nA; cB = nB; cC = nC; cD = nD;
    }
    // tail 0..3 edges (cA..cC hold csr[e..e+2])
    if (e < s1){
      float4 a = ((const float4*)(h + cA.x*32))[quad];
      float tA = 0.f; if (PRED) tA = tdot[cA.x];
      ACC1(cA, a, tA)
      if (e + 1 < s1){
        float4 b = ((const float4*)(h + cB.x*32))[quad];
        float tB = 0.f; if (PRED) tB = tdot[cB.x];
        ACC1(cB, b, tB)
        if (e + 2 < s1){
          float4 c4 = ((const float4*)(h + cC.x*32))[quad];
          float tC = 0.f; if (PRED) tC = tdot[cC.x];
          ACC1(cC, c4, tC)
        }
      }
    }
#undef ACC1

    // finalize (no cross-lane reduction needed)
    float bnd = (n == hv0) ? 0.f : 100.f;
    int deg = s1 - s0;
    float cntf = (float)(deg + 1);
#define FIN(cc, rc, S1c, S2c, Mc, mc) { \
    float mxv, mnv; \
    if (deg > 0){ \
      float em = (rc >= 0.f) ? rc*Mc : rc*mc; \
      float en = (rc >= 0.f) ? rc*mc : rc*Mc; \
      mxv = fmaxf(em, bnd); mnv = fminf(en, bnd); \
    } else { mxv = bnd; mnv = bnd; } \
    float meanv = (rc*S1c + bnd) / cntf; \
    float sq    = (rc*rc*S2c + bnd*bnd) / cntf; \
    float sdv   = sqrtf(fmaxf(sq - meanv*meanv, 1e-6f)); \
    int d = quad*4 + cc; \
    sh[(d*4+0)*65 + nl] = meanv; \
    sh[(d*4+1)*65 + nl] = mxv; \
    sh[(d*4+2)*65 + nl] = mnv; \
    sh[(d*4+3)*65 + nl] = sdv; }
    FIN(0, r4.x, S10, S20, M0, m0)
    FIN(1, r4.y, S11, S21, M1, m1)
    FIN(2, r4.z, S12, S22, M2, m2)
    FIN(3, r4.w, S13, S23, M3, m3)
#undef FIN
    if (PRED && valid && quad == 0){
      float ss = (n == hv0) ? 0.f : 3200.f;   // boundary self-loop row sum, w=1
      if (ss > best){ best = ss; bi = n; }
      else if (ss == best && n < bi) bi = n;
      pred_out[n] = (float)bi;
    }
  }
  __syncthreads();

  // ---- phase 2: linear (8 waves, wave w -> j0 = w*4; node = lane) ----
  // packed fp32: v2f arithmetic -> v_pk_fma_f32 (2 FLOPs/inst)
  {
    const float* Wl = lin_W + (size_t)l * 13312;   // 416*32
    int lane = tid & 63;
    int j0 = __builtin_amdgcn_readfirstlane((tid >> 6) * 4);  // 0,4,...,28
    int n0 = base + lane;
    int n = (n0 < NN) ? n0 : NN-1;
    float sc = scale_arr[n], iv = inv_arr[n];
    v2f a01, a23;
    a01[0] = lin_b[l*32 + j0 + 0]; a01[1] = lin_b[l*32 + j0 + 1];
    a23[0] = lin_b[l*32 + j0 + 2]; a23[1] = lin_b[l*32 + j0 + 3];

    for (int k = 0; k < 32; ++k){
      float xv = hT[k*NN + n];
      const v2f* wr2 = (const v2f*)(Wl + k*32 + j0);
      v2f xv2; xv2[0] = xv; xv2[1] = xv;
      a01 += xv2 * wr2[0];
      a23 += xv2 * wr2[1];
    }
    for (int kp = 0; kp < 128; ++kp){
      float f = sh[kp*65 + lane];
      int d = kp >> 2, c = kp & 3;
      const v2f* w2 = (const v2f*)(Wl + (32 + d*12 + c*3)*32 + j0);
      float f1 = f*sc, f2 = f*iv;
      v2f fv;  fv[0]=f;  fv[1]=f;
      v2f f1v; f1v[0]=f1; f1v[1]=f1;
      v2f f2v; f2v[0]=f2; f2v[1]=f2;
      // rows are 32 floats = 16 v2f apart
      a01 += fv*w2[0] + f1v*w2[16] + f2v*w2[32];
      a23 += fv*w2[1] + f1v*w2[17] + f2v*w2[33];
    }

    if (n0 < NN){
      float vs[4] = { a01[0], a01[1], a23[0], a23[1] };
      #pragma unroll
      for (int j = 0; j < 4; ++j){
        float v = fmaxf(vs[j], 0.f);
        h_next[n0*32 + j0 + j] = v;
        hT_next[(j0+j)*NN + n0] = v;
      }
    }
  }
}

// ---------------- final MLP ----------------
__global__ __launch_bounds__(256) void k_mlp(const float* __restrict__ hT,
                                             const float* __restrict__ qc,
                                             const float* __restrict__ W1,
                                             const float* __restrict__ W2,
                                             const float* __restrict__ b2,
                                             float* __restrict__ out_score){
  int n0 = blockIdx.x*256 + threadIdx.x;
  int n = (n0 < NN) ? n0 : NN-1;
  float acc[64];
  #pragma unroll
  for (int j = 0; j < 64; ++j) acc[j] = qc[j];
  for (int k = 0; k < 32; ++k){
    float xv = hT[k*NN + n];
    const float* wr = W1 + k*64;
    #pragma unroll
    for (int j = 0; j < 64; ++j) acc[j] += xv * wr[j];
  }
  float s = b2[0];
  #pragma unroll
  for (int j = 0; j < 64; ++j) s += fmaxf(acc[j], 0.f) * W2[j];
  if (n0 < NN) out_score[n0] = s;
}

// ---------------- host launch ----------------
extern "C" void kernel_launch(void* const* d_in, const int* in_sizes, int n_in,
                              void* d_out, int out_size, void* d_ws, size_t ws_size,
                              hipStream_t stream){
  const int*   node_in  = (const int*)d_in[0];
  const int*   node_out = (const int*)d_in[1];
  const float* ew       = (const float*)d_in[2];
  const int*   hidx     = (const int*)d_in[3];
  const float* qw       = (const float*)d_in[4];
  const float* rel_W    = (const float*)d_in[5];
  const float* rel_b    = (const float*)d_in[6];
  const float* lin_W    = (const float*)d_in[7];
  const float* lin_b    = (const float*)d_in[8];
  const float* W1       = (const float*)d_in[9];
  const float* b1       = (const float*)d_in[10];
  const float* W2       = (const float*)d_in[11];
  const float* b2       = (const float*)d_in[12];
  float* out_score = (float*)d_out;
  float* out_pred  = out_score + NN;

  char* w = (char*)d_ws;
  size_t off = 0;
  auto take = [&](size_t bytes)->char*{
    char* p = w + off;
    off = (off + bytes + 255) & ~(size_t)255;
    return p;
  };
  double* deg_pack = (double*)take((size_t)NN*8 + 64*4);
  float*  logsum   = (float*)(deg_pack + NN);
  int*   row_start = (int*)take((size_t)(NN+1)*4);
  int*   cursor    = (int*)take((size_t)NN*4);
  int*   partials  = (int*)take(256*4);
  float* rel6      = (float*)take(192*4);
  float* qc        = (float*)take(64*4);
  float* scale_arr = (float*)take((size_t)NN*4);
  float* inv_arr   = (float*)take((size_t)NN*4);
  float* tdot      = (float*)take((size_t)NN*4);
  int2*  csr       = (int2*)take((size_t)(EE+32)*8);
  float* h_a       = (float*)take((size_t)NN*32*4);
  float* hT_a      = (float*)take((size_t)NN*32*4);
  float* h_b       = (float*)take((size_t)NN*32*4);
  float* hT_b      = (float*)take((size_t)NN*32*4);

  int zc = 2*NN + 64;   // N doubles == 2N floats, + logsum block
  int nb = (NN + 255) / 256;   // 196
  int nlb = (NN + 63) / 64;    // 782
  k_zero   <<<(zc+255)/256, 256, 0, stream>>>((float*)deg_pack, zc);
  k_hist   <<<(EE+255)/256, 256, 0, stream>>>(node_out, ew, deg_pack);
  k_logsum <<<nb, 256, 0, stream>>>(deg_pack, logsum);
  k_scan1  <<<nb, 256, 0, stream>>>(deg_pack, partials);
  k_scan2  <<<1, 256, 0, stream>>>(partials, nb, row_start, csr);
  k_scan3  <<<nb, 256, 0, stream>>>(deg_pack, partials, row_start, cursor);
  k_fillcsr<<<(EE+255)/256, 256, 0, stream>>>(node_in, node_out, ew, cursor, csr);
  k_scales <<<nb, 256, 0, stream>>>(deg_pack, logsum, scale_arr, inv_arr);
  k_prep   <<<1, 256, 0, stream>>>(qw, rel_W, rel_b, W1, b1, rel6, qc);
  k_init_h <<<(NN*DD+255)/256, 256, 0, stream>>>(hidx, h_a, hT_a);

  float* hc = h_a;  float* hTc = hT_a;
  float* hn = h_b;  float* hTn = hT_b;
  for (int l = 0; l < 6; ++l){
    if (l == 5){
      k_dot<<<nb, 256, 0, stream>>>(hc, rel6, tdot);
      k_layer<true><<<nlb, 512, 0, stream>>>(hc, hTc, rel6, row_start, csr,
                                             hidx, tdot, lin_W, lin_b,
                                             scale_arr, inv_arr, hn, hTn,
                                             out_pred, l);
    } else {
      k_layer<false><<<nlb, 512, 0, stream>>>(hc, hTc, rel6, row_start, csr,
                                              hidx, tdot, lin_W, lin_b,
                                              scale_arr, inv_arr, hn, hTn,
                                              out_pred, l);
    }
    float* t1 = hc;  hc = hn;  hn = t1;
    float* t2 = hTc; hTc = hTn; hTn = t2;
  }
  k_mlp<<<nb, 256, 0, stream>>>(hTc, qc, W1, W2, b2, out_score);
}